// Round 8
// baseline (300.987 us; speedup 1.0000x reference)
//
#include <hip/hip_runtime.h>

// ---- problem constants ----
#define BB 2
#define SS 1024
#define HIDDEN 2880
#define NH 64
#define NKV 8
#define HD 64
#define M_TOK 2048          // B*S
#define NQ 4096             // NH*HD
#define NKVD 512            // NKV*HD
#define NQKV 5120           // NQ + 2*NKVD
#define NOUT 2880
#define NOUT_PAD 3072       // 12*256
#define PART_ELEMS 10485760 // 2048*5120 elements per QKV partial

typedef __attribute__((ext_vector_type(8))) short short8;
typedef __attribute__((ext_vector_type(4))) float f32x4;

__device__ __forceinline__ unsigned short f2b(float x) {
  union { float f; unsigned u; } v; v.f = x;
  unsigned r = (v.u + 0x7FFFu + ((v.u >> 16) & 1u)) >> 16;
  return (unsigned short)r;
}
__device__ __forceinline__ float b2f(unsigned short u) {
  union { unsigned u; float f; } v; v.u = ((unsigned)u) << 16; return v.f;
}

__device__ __forceinline__ void gload16(const void* g, void* l) {
  __builtin_amdgcn_global_load_lds(
      (const __attribute__((address_space(1))) void*)g,
      (__attribute__((address_space(3))) void*)l, 16, 0, 0);
}

#define BAR()  asm volatile("s_barrier" ::: "memory")
#define VMC(n) asm volatile("s_waitcnt vmcnt(" #n ")" ::: "memory")

// ---- cast x (fp32 -> bf16), vectorized ----
__global__ __launch_bounds__(256) void cast_x_kernel(const float* __restrict__ in,
                                                     unsigned short* __restrict__ out,
                                                     int n4) {
  int idx = blockIdx.x * 256 + threadIdx.x;
  if (idx >= n4) return;
  float4 v = ((const float4*)in)[idx];
  ushort4 o;
  o.x = f2b(v.x); o.y = f2b(v.y); o.z = f2b(v.z); o.w = f2b(v.w);
  ((ushort4*)out)[idx] = o;
}

// ---- transpose + cast (fp32 in): out[n*K + k] = (bf16) in[k*ldin + n] ----
__global__ __launch_bounds__(256) void transpose_cast(const float* __restrict__ in,
                                                      long ldin,
                                                      unsigned short* __restrict__ out,
                                                      int K, int N) {
  __shared__ float t[32][33];
  const int n0 = blockIdx.x * 32, k0 = blockIdx.y * 32;
  const int tx = threadIdx.x, ty = threadIdx.y;
#pragma unroll
  for (int i = 0; i < 4; ++i) {
    int k = k0 + ty + i * 8;
    int n = n0 + tx;
    t[ty + i * 8][tx] = (n < N) ? in[(long)k * ldin + n] : 0.f;
  }
  __syncthreads();
#pragma unroll
  for (int i = 0; i < 4; ++i) {
    int n = n0 + ty + i * 8;
    int k = k0 + tx;
    out[(long)n * K + k] = f2b(t[tx][ty + i * 8]);
  }
}

// ---- RoPE cos/sin table ----
__global__ __launch_bounds__(256) void rope_table(const int* __restrict__ pos,
                                                  float* __restrict__ ct,
                                                  float* __restrict__ st) {
  int tid = blockIdx.x * 256 + threadIdx.x;   // < 2048*32
  int t = tid >> 5, i = tid & 31;
  float p = (float)pos[t];
  float f = p * expf(-(float)i * (11.918390573078392f / 32.f));
  ct[tid] = cosf(f);
  st[tid] = sinf(f);
}

// ---- RoPE + pack q from 3 bf16 partials (pre-scaled by 1/8) ----
__global__ __launch_bounds__(256) void rope_q_pack3(const unsigned short* __restrict__ part,
                                                    const float* __restrict__ ct,
                                                    const float* __restrict__ st,
                                                    unsigned short* __restrict__ qb) {
  int tid = blockIdx.x * 256 + threadIdx.x;   // < 2048*64*32
  int i = tid & 31;
  int h = (tid >> 5) & 63;
  int t = tid >> 11;
  const unsigned short* sp = part + (size_t)t * NQKV + h * 64;
  float x1 = b2f(sp[i]) + b2f(sp[i + (size_t)PART_ELEMS]) + b2f(sp[i + 2 * (size_t)PART_ELEMS]);
  float x2 = b2f(sp[i + 32]) + b2f(sp[i + 32 + (size_t)PART_ELEMS]) + b2f(sp[i + 32 + 2 * (size_t)PART_ELEMS]);
  float c = ct[t * 32 + i], s = st[t * 32 + i];
  int b = t >> 10, sidx = t & 1023;
  unsigned short* dst = qb + (((size_t)(b * NH + h)) * SS + sidx) * HD;
  dst[i]      = f2b((x1 * c - x2 * s) * 0.125f);
  dst[i + 32] = f2b((x1 * s + x2 * c) * 0.125f);
}

// ---- RoPE + pack k from 3 bf16 partials ----
__global__ __launch_bounds__(256) void rope_k_pack3(const unsigned short* __restrict__ part,
                                                    const float* __restrict__ ct,
                                                    const float* __restrict__ st,
                                                    unsigned short* __restrict__ kb) {
  int tid = blockIdx.x * 256 + threadIdx.x;   // < 2048*8*32
  int i = tid & 31;
  int h = (tid >> 5) & 7;
  int t = tid >> 8;
  const unsigned short* sp = part + (size_t)t * NQKV + NQ + h * 64;
  float x1 = b2f(sp[i]) + b2f(sp[i + (size_t)PART_ELEMS]) + b2f(sp[i + 2 * (size_t)PART_ELEMS]);
  float x2 = b2f(sp[i + 32]) + b2f(sp[i + 32 + (size_t)PART_ELEMS]) + b2f(sp[i + 32 + 2 * (size_t)PART_ELEMS]);
  float c = ct[t * 32 + i], s = st[t * 32 + i];
  int b = t >> 10, sidx = t & 1023;
  unsigned short* dst = kb + (((size_t)(b * NKV + h)) * SS + sidx) * HD;
  dst[i]      = f2b(x1 * c - x2 * s);
  dst[i + 32] = f2b(x1 * s + x2 * c);
}

// ---- v pack: transpose + sum3: vtb[b][d][s] = sum_p part[p][b*1024+s][4608+d] ----
__global__ __launch_bounds__(256) void v_pack3(const unsigned short* __restrict__ part,
                                               unsigned short* __restrict__ vtb) {
  __shared__ float t[32][33];
  const int n0 = blockIdx.x * 32;              // d (0..511)
  const int b  = blockIdx.y >> 5;
  const int k0 = (blockIdx.y & 31) * 32;       // s (0..1023)
  const int tx = threadIdx.x, ty = threadIdx.y;
#pragma unroll
  for (int i = 0; i < 4; ++i) {
    int k = k0 + ty + i * 8;
    int n = n0 + tx;
    const unsigned short* sp = part + (size_t)(b * 1024 + k) * NQKV + (NQ + NKVD) + n;
    t[ty + i * 8][tx] = b2f(sp[0]) + b2f(sp[(size_t)PART_ELEMS]) + b2f(sp[2 * (size_t)PART_ELEMS]);
  }
  __syncthreads();
#pragma unroll
  for (int i = 0; i < 4; ++i) {
    int n = n0 + ty + i * 8;
    int k = k0 + tx;
    vtb[((size_t)(b * NKVD + n)) * SS + k] = f2b(t[tx][ty + i * 8]);
  }
}

// ==== GEMM 256x256, BK=64, 8 waves, counted-vmcnt (T4) 2-half schedule ====
// C(bf16) = A_bf16[M][lda] x Bt_bf16[N][lda]^T over Kloop cols starting at z*Kloop.
// Race-free invariant: all stages for tile t+1 target buf^1 (never the read buffer).
// Per-tile stage FIFO: A0',B0',B1',A1' (8 gloads). Waits:
//   mid-tile : vmcnt(8)+bar  -> THIS tile's A1 landed (8 = next tile's stages in flight)
//   tile end : vmcnt(2)+bar  -> next tile's A0,B0,B1 landed (A1' still flying)
// Tail (no more stages): mid vmcnt(0); end no wait needed.
__global__ __launch_bounds__(512, 2) void gemm256(const unsigned short* __restrict__ A,
                                                  const unsigned short* __restrict__ Bt,
                                                  unsigned short* __restrict__ C0,
                                                  unsigned short* __restrict__ C1,
                                                  unsigned short* __restrict__ C2,
                                                  unsigned short* __restrict__ C3,
                                                  int lda, int Kloop, int ldc, int Nvalid) {
  __shared__ short8 ldsA[2 * 2048];   // 2 bufs x 32KB
  __shared__ short8 ldsB[2 * 2048];
  char* lAc = (char*)ldsA;
  char* lBc = (char*)ldsB;
  const int tid = threadIdx.x;
  const int lane = tid & 63;
  const int w = tid >> 6;
  const int m16 = lane & 15, g4 = lane >> 4;
  const int wr = w >> 2;              // 0..1  (M wave-row)
  const int wc = w & 3;               // 0..3  (N wave-col)
  const int bm = blockIdx.y * 256, bn = blockIdx.x * 256;
  const int z = blockIdx.z;
  unsigned short* __restrict__ Cw = (z == 0) ? C0 : ((z == 1) ? C1 : ((z == 2) ? C2 : C3));
  const size_t strAb = (size_t)lda * 2;            // row stride bytes
  const size_t koffb = (size_t)z * Kloop * 2;      // split-K byte offset
  const char* gAc = (const char*)A;
  const char* gBc = (const char*)Bt;

  // staging: 512 threads x 16B = 8KB = 64 rows x 128B per gload issue
  const int srow = tid >> 3;                                   // 0..63
  const int scolb = ((tid & 7) * 16) ^ ((srow & 7) << 4);      // inverse-swizzled src col
  const int sdst = w * 1024;                                   // wave-uniform dest

  auto stA = [&](int buf, int half, int kt) {
    const char* src = gAc + (size_t)(bm + half * 128 + srow) * strAb + koffb + (size_t)kt * 128 + scolb;
    char* dst = lAc + buf * 32768 + half * 16384 + sdst;
    gload16(src, dst);
    gload16(src + 64 * strAb, dst + 8192);
  };
  auto stB = [&](int buf, int half, int kt) {
    const char* src = gBc + (size_t)(bn + half * 128 + srow) * strAb + koffb + (size_t)kt * 128 + scolb;
    char* dst = lBc + buf * 32768 + half * 16384 + sdst;
    gload16(src, dst);
    gload16(src + 64 * strAb, dst + 8192);
  };

  // fragment reads (swizzled): global(row, kb) lives at LDS(row, kb ^ ((row&7)<<4))
  const int swz = (m16 & 7) << 4;
  const int kc0 = (g4 * 16) ^ swz;
  const int kc1 = (64 + g4 * 16) ^ swz;

  f32x4 acc[8][4];
#pragma unroll
  for (int i = 0; i < 8; ++i)
#pragma unroll
    for (int j = 0; j < 4; ++j) acc[i][j] = (f32x4){0.f, 0.f, 0.f, 0.f};
  short8 afr[4][2], bf0[2][2], bf1[2][2];

#define LOAD_A(bo, mh) { _Pragma("unroll") for (int mq = 0; mq < 4; ++mq) {                     \
    const int row = (mh) * 128 + wr * 64 + mq * 16 + m16;                                       \
    afr[mq][0] = *(const short8*)(lAc + (bo) + row * 128 + kc0);                                \
    afr[mq][1] = *(const short8*)(lAc + (bo) + row * 128 + kc1); } }
#define LOAD_B(bo, nh, dstf) { _Pragma("unroll") for (int nf = 0; nf < 2; ++nf) {               \
    const int row = (nh) * 128 + wc * 32 + nf * 16 + m16;                                       \
    dstf[nf][0] = *(const short8*)(lBc + (bo) + row * 128 + kc0);                               \
    dstf[nf][1] = *(const short8*)(lBc + (bo) + row * 128 + kc1); } }
#define MFMA_Q(mh, nh, bff) { __builtin_amdgcn_s_setprio(1);                                    \
  _Pragma("unroll") for (int mq = 0; mq < 4; ++mq)                                              \
  _Pragma("unroll") for (int nf = 0; nf < 2; ++nf) {                                            \
    acc[(mh)*4+mq][(nh)*2+nf] = __builtin_amdgcn_mfma_f32_16x16x32_bf16(                        \
        afr[mq][0], bff[nf][0], acc[(mh)*4+mq][(nh)*2+nf], 0, 0, 0);                            \
    acc[(mh)*4+mq][(nh)*2+nf] = __builtin_amdgcn_mfma_f32_16x16x32_bf16(                        \
        afr[mq][1], bff[nf][1], acc[(mh)*4+mq][(nh)*2+nf], 0, 0, 0); }                          \
  __builtin_amdgcn_s_setprio(0); }

  const int NT = Kloop >> 6;
  // prologue: stage tile0 into buf0 (FIFO A0,B0,B1,A1), drain, sync
  stA(0, 0, 0); stB(0, 0, 0); stB(0, 1, 0); stA(0, 1, 0);
  VMC(0);
  BAR();

  for (int t = 0; t < NT; ++t) {
    const int buf = t & 1;
    const int bo = buf * 32768;
    const int nb = buf ^ 1;
    const bool more = (t + 1 < NT);
    if (more) {   // stage tile t+1 (FIFO: A0',B0',B1',A1') into the other buffer
      stA(nb, 0, t + 1); stB(nb, 0, t + 1);
      stB(nb, 1, t + 1); stA(nb, 1, t + 1);
    }
    // half 1: quadrants (0,0), (0,1) -- consumes A0, B0, B1
    LOAD_B(bo, 0, bf0);
    LOAD_A(bo, 0);
    MFMA_Q(0, 0, bf0);
    LOAD_B(bo, 1, bf1);
    MFMA_Q(0, 1, bf1);
    if (more) { VMC(8); } else { VMC(0); }   // this tile's A1 landed
    BAR();
    // half 2: quadrants (1,1), (1,0) -- consumes A1 (B0,B1 from regs)
    LOAD_A(bo, 1);
    MFMA_Q(1, 1, bf1);
    MFMA_Q(1, 0, bf0);
    if (more) { VMC(2); }                    // next tile's A0,B0,B1 landed
    BAR();
  }
#undef LOAD_A
#undef LOAD_B
#undef MFMA_Q

  // epilogue (bf16): row = bm + mh*128 + wr*64 + mq*16 + g4*4 + r ; col = bn + nh*128 + wc*32 + nf*16 + m16
#pragma unroll
  for (int mi = 0; mi < 8; ++mi) {
    const int mh = mi >> 2, mq = mi & 3;
    const size_t row = bm + mh * 128 + wr * 64 + mq * 16 + g4 * 4;
#pragma unroll
    for (int ni = 0; ni < 4; ++ni) {
      const int nh = ni >> 1, nf = ni & 1;
      const int col = bn + nh * 128 + wc * 32 + nf * 16 + m16;
      if (col < Nvalid) {
#pragma unroll
        for (int r = 0; r < 4; ++r)
          Cw[(row + r) * (size_t)ldc + col] = f2b(acc[mi][ni][r]);
      }
    }
  }
}

// ---- split-K reduce: out[2048][2880] fp32 = p0+p1+p2+p3 (bf16 [2048][3072] each) ----
__global__ __launch_bounds__(256) void reduce_wo4(const unsigned short* __restrict__ p0,
                                                  const unsigned short* __restrict__ p1,
                                                  const unsigned short* __restrict__ p2,
                                                  const unsigned short* __restrict__ p3,
                                                  float* __restrict__ out) {
  int idx = blockIdx.x * 256 + threadIdx.x;   // < 2048*720
  int row = idx / 720, c4 = idx - row * 720;
  const size_t o = (size_t)row * 3072 + c4 * 4;
  const ushort4 a = *(const ushort4*)(p0 + o);
  const ushort4 b = *(const ushort4*)(p1 + o);
  const ushort4 c = *(const ushort4*)(p2 + o);
  const ushort4 d = *(const ushort4*)(p3 + o);
  float4 r;
  r.x = (b2f(a.x) + b2f(b.x)) + (b2f(c.x) + b2f(d.x));
  r.y = (b2f(a.y) + b2f(b.y)) + (b2f(c.y) + b2f(d.y));
  r.z = (b2f(a.z) + b2f(b.z)) + (b2f(c.z) + b2f(d.z));
  r.w = (b2f(a.w) + b2f(b.w)) + (b2f(c.w) + b2f(d.w));
  *(float4*)(out + (size_t)row * 2880 + c4 * 4) = r;
}

// ---- flash attention (unchanged, validated R2-R6) ----
__global__ __launch_bounds__(512) void attn_fwd(const unsigned short* __restrict__ qb,
                                                const unsigned short* __restrict__ kb,
                                                const unsigned short* __restrict__ vtb,
                                                unsigned short* __restrict__ ao) {
  __shared__ unsigned short kB[2][64 * 64];
  __shared__ unsigned short vB[2][64 * 64];
  __shared__ unsigned short pB[8][32 * 64];
  const int tid = threadIdx.x, lane = tid & 63, w = tid >> 6;
  const int qblk = blockIdx.x;
  const int bh = blockIdx.y;
  const int b = bh >> 6, h = bh & 63, hkv = h >> 3;
  const int m16 = lane & 15, g4 = lane >> 4;
  const int rbase = qblk * 256 + w * 32;

  const unsigned short* qp =
      qb + (((size_t)(b * NH + h)) * SS + rbase + m16) * HD + g4 * 8;
  const short8 q00 = *(const short8*)(qp);
  const short8 q01 = *(const short8*)(qp + 32);
  const short8 q10 = *(const short8*)(qp + 16 * HD);
  const short8 q11 = *(const short8*)(qp + 16 * HD + 32);

  const char* kbp = (const char*)(kb + ((size_t)(b * NKV + hkv)) * SS * HD);
  const char* vbp = (const char*)(vtb + ((size_t)(b * NKV + hkv)) * HD * SS);

  const int lrow = lane >> 3;
  const int lcolb = ((lane & 7) * 16) ^ ((lrow & 7) << 4);
  unsigned short* kDst0 = &kB[0][w * 512];
  unsigned short* kDst1 = &kB[1][w * 512];
  unsigned short* vDst0 = &vB[0][w * 512];
  unsigned short* vDst1 = &vB[1][w * 512];
  const size_t kRowOff = (size_t)(w * 8 + lrow) * 128 + lcolb;
  const size_t vRowOff = (size_t)(w * 8 + lrow) * 2048 + lcolb;

  const short8 ones = {(short)0x3F80, (short)0x3F80, (short)0x3F80, (short)0x3F80,
                       (short)0x3F80, (short)0x3F80, (short)0x3F80, (short)0x3F80};

  f32x4 o0[4], o1[4];
#pragma unroll
  for (int n = 0; n < 4; ++n) { o0[n] = (f32x4){0,0,0,0}; o1[n] = (f32x4){0,0,0,0}; }
  f32x4 lacc0 = (f32x4){0,0,0,0}, lacc1 = (f32x4){0,0,0,0};
  float mrow0[4] = {-1e30f,-1e30f,-1e30f,-1e30f};
  float mrow1[4] = {-1e30f,-1e30f,-1e30f,-1e30f};

  char* pw = (char*)pB[w];
  const int swz_m = (m16 & 7) << 4;
  const int nt = (qblk + 1) * 4;

  gload16(kbp + kRowOff, kDst0);
  gload16(vbp + vRowOff, vDst0);
  __syncthreads();

  for (int t = 0; t < nt; ++t) {
    const int k0 = t * 64;
    const char* kLds = (const char*)kB[t & 1];
    const char* vLds = (const char*)vB[t & 1];
    if (t + 1 < nt) {
      if (t & 1) { gload16(kbp + (size_t)(t + 1) * 8192 + kRowOff, kDst0);
                   gload16(vbp + (size_t)(t + 1) * 128  + vRowOff, vDst0); }
      else       { gload16(kbp + (size_t)(t + 1) * 8192 + kRowOff, kDst1);
                   gload16(vbp + (size_t)(t + 1) * 128  + vRowOff, vDst1); }
    }
    if (k0 < rbase + 32) {
      short8 kf0[4], kf1[4];
#pragma unroll
      for (int kf = 0; kf < 4; ++kf) {
        const int rb = (kf * 16 + m16) * 128;
        kf0[kf] = *(const short8*)(kLds + ((rb + g4 * 16) ^ swz_m));
        kf1[kf] = *(const short8*)(kLds + ((rb + 64 + g4 * 16) ^ swz_m));
      }
      f32x4 s0[4], s1[4];
      __builtin_amdgcn_s_setprio(1);
#pragma unroll
      for (int kf = 0; kf < 4; ++kf) {
        f32x4 z = (f32x4){0,0,0,0};
        z = __builtin_amdgcn_mfma_f32_16x16x32_bf16(q00, kf0[kf], z, 0, 0, 0);
        z = __builtin_amdgcn_mfma_f32_16x16x32_bf16(q01, kf1[kf], z, 0, 0, 0);
        s0[kf] = z;
        f32x4 z2 = (f32x4){0,0,0,0};
        z2 = __builtin_amdgcn_mfma_f32_16x16x32_bf16(q10, kf0[kf], z2, 0, 0, 0);
        z2 = __builtin_amdgcn_mfma_f32_16x16x32_bf16(q11, kf1[kf], z2, 0, 0, 0);
        s1[kf] = z2;
      }
      __builtin_amdgcn_s_setprio(0);
      if (k0 + 63 >= rbase) {
#pragma unroll
        for (int kf = 0; kf < 4; ++kf)
#pragma unroll
          for (int r = 0; r < 4; ++r) {
            const int col = k0 + kf * 16 + m16;
            if (col > rbase + g4 * 4 + r)      s0[kf][r] = -1e30f;
            if (col > rbase + 16 + g4 * 4 + r) s1[kf][r] = -1e30f;
          }
      }
      int grow = 0;
#pragma unroll
      for (int kf = 0; kf < 4; ++kf)
#pragma unroll
        for (int r = 0; r < 4; ++r) {
          grow |= (s0[kf][r] > mrow0[r] + 8.f);
          grow |= (s1[kf][r] > mrow1[r] + 8.f);
        }
      if (__any(grow)) {
        float mx0[4], mx1[4];
#pragma unroll
        for (int r = 0; r < 4; ++r) {
          mx0[r] = fmaxf(fmaxf(s0[0][r], s0[1][r]), fmaxf(s0[2][r], s0[3][r]));
          mx1[r] = fmaxf(fmaxf(s1[0][r], s1[1][r]), fmaxf(s1[2][r], s1[3][r]));
        }
#pragma unroll
        for (int off = 1; off <= 8; off <<= 1)
#pragma unroll
          for (int r = 0; r < 4; ++r) {
            mx0[r] = fmaxf(mx0[r], __shfl_xor(mx0[r], off));
            mx1[r] = fmaxf(mx1[r], __shfl_xor(mx1[r], off));
          }
#pragma unroll
        for (int r = 0; r < 4; ++r) {
          float mn0 = fmaxf(mrow0[r], mx0[r]);
          float sc0 = __expf(mrow0[r] - mn0);
          mrow0[r] = mn0; lacc0[r] *= sc0;
          float mn1 = fmaxf(mrow1[r], mx1[r]);
          float sc1 = __expf(mrow1[r] - mn1);
          mrow1[r] = mn1; lacc1[r] *= sc1;
#pragma unroll
          for (int n = 0; n < 4; ++n) { o0[n][r] *= sc0; o1[n][r] *= sc1; }
        }
      }
#pragma unroll
      for (int kf = 0; kf < 4; ++kf)
#pragma unroll
        for (int r = 0; r < 4; ++r) {
          const int colb = (kf * 16 + m16) * 2;
          int row = g4 * 4 + r;
          *(unsigned short*)(pw + ((row * 128 + colb) ^ ((row & 7) << 4))) =
              f2b(__expf(s0[kf][r] - mrow0[r]));
          row += 16;
          *(unsigned short*)(pw + ((row * 128 + colb) ^ ((row & 7) << 4))) =
              f2b(__expf(s1[kf][r] - mrow1[r]));
        }
      const int prb0 = m16 * 128, prb1 = (16 + m16) * 128;
      short8 pf00 = *(const short8*)(pw + ((prb0 + g4 * 16) ^ swz_m));
      short8 pf01 = *(const short8*)(pw + ((prb0 + 64 + g4 * 16) ^ swz_m));
      short8 pf10 = *(const short8*)(pw + ((prb1 + g4 * 16) ^ swz_m));
      short8 pf11 = *(const short8*)(pw + ((prb1 + 64 + g4 * 16) ^ swz_m));
      __builtin_amdgcn_s_setprio(1);
      lacc0 = __builtin_amdgcn_mfma_f32_16x16x32_bf16(pf00, ones, lacc0, 0, 0, 0);
      lacc0 = __builtin_amdgcn_mfma_f32_16x16x32_bf16(pf01, ones, lacc0, 0, 0, 0);
      lacc1 = __builtin_amdgcn_mfma_f32_16x16x32_bf16(pf10, ones, lacc1, 0, 0, 0);
      lacc1 = __builtin_amdgcn_mfma_f32_16x16x32_bf16(pf11, ones, lacc1, 0, 0, 0);
#pragma unroll
      for (int n = 0; n < 4; ++n) {
        const int rb = (n * 16 + m16) * 128;
        short8 vf0 = *(const short8*)(vLds + ((rb + g4 * 16) ^ swz_m));
        short8 vf1 = *(const short8*)(vLds + ((rb + 64 + g4 * 16) ^ swz_m));
        o0[n] = __builtin_amdgcn_mfma_f32_16x16x32_bf16(pf00, vf0, o0[n], 0, 0, 0);
        o0[n] = __builtin_amdgcn_mfma_f32_16x16x32_bf16(pf01, vf1, o0[n], 0, 0, 0);
        o1[n] = __builtin_amdgcn_mfma_f32_16x16x32_bf16(pf10, vf0, o1[n], 0, 0, 0);
        o1[n] = __builtin_amdgcn_mfma_f32_16x16x32_bf16(pf11, vf1, o1[n], 0, 0, 0);
      }
      __builtin_amdgcn_s_setprio(0);
    }
    __syncthreads();
  }

  float inv0[4], inv1[4];
#pragma unroll
  for (int r = 0; r < 4; ++r) { inv0[r] = 1.f / lacc0[r]; inv1[r] = 1.f / lacc1[r]; }
  const size_t row0 = (size_t)b * SS + rbase + g4 * 4;
#pragma unroll
  for (int n = 0; n < 4; ++n)
#pragma unroll
    for (int r = 0; r < 4; ++r) {
      ao[(row0 + r) * (size_t)NQ + h * 64 + n * 16 + m16] = f2b(o0[n][r] * inv0[r]);
      ao[(row0 + 16 + r) * (size_t)NQ + h * 64 + n * 16 + m16] = f2b(o1[n][r] * inv1[r]);
    }
}

// ---- workspace layout (bytes) ----
// Region A (0..41,287,680):   xb(11.8M)+wqkvt(29.5M)  [live thru QKV gemm]
//   then: wot bf16 [3072][4096] @0 (25.2M); wo p1 @25,165,824 (12.6M)
// Region B (41,287,680..104,202,240): QKV partials bf16 [3][2048][5120] (62.9M)
//   then: attnb @41,287,680 (16.8M); wo p0 @58,064,896; p2 @70,647,808; p3 @83,230,720
constexpr size_t OFF_XB    = 0;
constexpr size_t OFF_WQKVT = 11796480;
constexpr size_t OFF_PART  = 41287680;
constexpr size_t OFF_WOT   = 0;
constexpr size_t OFF_P1    = 25165824;
constexpr size_t OFF_ATTNB = 41287680;
constexpr size_t OFF_P0    = 58064896;
constexpr size_t OFF_P2    = 70647808;
constexpr size_t OFF_P3    = 83230720;
constexpr size_t OFF_CT    = 104202240;
constexpr size_t OFF_ST    = 104464384;
constexpr size_t OFF_QB    = 104726528;
constexpr size_t OFF_KB    = 121503744;
constexpr size_t OFF_VTB   = 123600896;

extern "C" void kernel_launch(void* const* d_in, const int* in_sizes, int n_in,
                              void* d_out, int out_size, void* d_ws, size_t ws_size,
                              hipStream_t stream) {
  const float* x  = (const float*)d_in[0];
  const float* wq = (const float*)d_in[1];
  const float* wk = (const float*)d_in[2];
  const float* wv = (const float*)d_in[3];
  const float* wo = (const float*)d_in[4];
  const int* pos  = (const int*)d_in[5];
  float* out = (float*)d_out;
  char* ws = (char*)d_ws;

  unsigned short* xb    = (unsigned short*)(ws + OFF_XB);
  unsigned short* wqkvt = (unsigned short*)(ws + OFF_WQKVT);
  unsigned short* part  = (unsigned short*)(ws + OFF_PART);
  unsigned short* wot   = (unsigned short*)(ws + OFF_WOT);
  unsigned short* p0    = (unsigned short*)(ws + OFF_P0);
  unsigned short* p1    = (unsigned short*)(ws + OFF_P1);
  unsigned short* p2    = (unsigned short*)(ws + OFF_P2);
  unsigned short* p3    = (unsigned short*)(ws + OFF_P3);
  unsigned short* attnb = (unsigned short*)(ws + OFF_ATTNB);
  float* ct             = (float*)(ws + OFF_CT);
  float* st             = (float*)(ws + OFF_ST);
  unsigned short* qbuf  = (unsigned short*)(ws + OFF_QB);
  unsigned short* kbuf  = (unsigned short*)(ws + OFF_KB);
  unsigned short* vtb   = (unsigned short*)(ws + OFF_VTB);

  cast_x_kernel<<<(M_TOK * HIDDEN / 4 + 255) / 256, 256, 0, stream>>>(x, xb, M_TOK * HIDDEN / 4);
  rope_table<<<(M_TOK * 32) / 256, 256, 0, stream>>>(pos, ct, st);
  transpose_cast<<<dim3(NQ / 32, HIDDEN / 32), dim3(32, 8), 0, stream>>>(
      wq, NQ, wqkvt, HIDDEN, NQ);
  transpose_cast<<<dim3(NKVD / 32, HIDDEN / 32), dim3(32, 8), 0, stream>>>(
      wk, NKVD, wqkvt + (size_t)NQ * HIDDEN, HIDDEN, NKVD);
  transpose_cast<<<dim3(NKVD / 32, HIDDEN / 32), dim3(32, 8), 0, stream>>>(
      wv, NKVD, wqkvt + (size_t)(NQ + NKVD) * HIDDEN, HIDDEN, NKVD);
  // QKV projection: split-K=3 (K=3x960), grid 20x8x3 = 480 blocks, bf16 partials
  gemm256<<<dim3(NQKV / 256, M_TOK / 256, 3), 512, 0, stream>>>(
      xb, wqkvt, part, part + (size_t)PART_ELEMS, part + 2 * (size_t)PART_ELEMS, nullptr,
      HIDDEN, HIDDEN / 3, NQKV, NQKV);
  // wo transpose into region A (xb/wqkvt now dead)
  transpose_cast<<<dim3(NOUT_PAD / 32, NQ / 32), dim3(32, 8), 0, stream>>>(
      wo, NOUT, wot, NQ, NOUT);
  // RoPE + pack (sums the 3 partials)
  rope_q_pack3<<<(M_TOK * NH * 32) / 256, 256, 0, stream>>>(part, ct, st, qbuf);
  rope_k_pack3<<<(M_TOK * NKV * 32) / 256, 256, 0, stream>>>(part, ct, st, kbuf);
  v_pack3<<<dim3(NKVD / 32, BB * 32), dim3(32, 8), 0, stream>>>(part, vtb);
  // attention (partials dead; attnb overlays part[0])
  attn_fwd<<<dim3(4, BB * NH), 512, 0, stream>>>(qbuf, kbuf, vtb, attnb);
  // output projection: split-K=4 (K=4x1024), grid 12x8x4 = 384 blocks, bf16 partials
  gemm256<<<dim3(NOUT_PAD / 256, M_TOK / 256, 4), 512, 0, stream>>>(
      attnb, wot, p0, p1, p2, p3, NQ, NQ / 4, NOUT_PAD, NOUT_PAD);
  reduce_wo4<<<(M_TOK * 720) / 256, 256, 0, stream>>>(p0, p1, p2, p3, out);
}

// Round 9
// 298.948 us; speedup vs baseline: 1.0068x; 1.0068x over previous
//
#include <hip/hip_runtime.h>

// ---- problem constants ----
#define BB 2
#define SS 1024
#define HIDDEN 2880
#define NH 64
#define NKV 8
#define HD 64
#define M_TOK 2048          // B*S
#define NQ 4096             // NH*HD
#define NKVD 512            // NKV*HD
#define NQKV 5120           // NQ + 2*NKVD
#define NOUT 2880
#define NOUT_PAD 3072       // 12*256
#define PART_ELEMS 10485760 // 2048*5120 elements per QKV partial

typedef __attribute__((ext_vector_type(8))) short short8;
typedef __attribute__((ext_vector_type(4))) float f32x4;

__device__ __forceinline__ unsigned short f2b(float x) {
  union { float f; unsigned u; } v; v.f = x;
  unsigned r = (v.u + 0x7FFFu + ((v.u >> 16) & 1u)) >> 16;
  return (unsigned short)r;
}
__device__ __forceinline__ float b2f(unsigned short u) {
  union { unsigned u; float f; } v; v.u = ((unsigned)u) << 16; return v.f;
}

__device__ __forceinline__ void gload16(const void* g, void* l) {
  __builtin_amdgcn_global_load_lds(
      (const __attribute__((address_space(1))) void*)g,
      (__attribute__((address_space(3))) void*)l, 16, 0, 0);
}

#define BAR()  asm volatile("s_barrier" ::: "memory")
#define VMC(n) asm volatile("s_waitcnt vmcnt(" #n ")" ::: "memory")
#define LGK0() asm volatile("s_waitcnt lgkmcnt(0)" ::: "memory")

// ---- cast x (fp32 -> bf16), vectorized ----
__global__ __launch_bounds__(256) void cast_x_kernel(const float* __restrict__ in,
                                                     unsigned short* __restrict__ out,
                                                     int n4) {
  int idx = blockIdx.x * 256 + threadIdx.x;
  if (idx >= n4) return;
  float4 v = ((const float4*)in)[idx];
  ushort4 o;
  o.x = f2b(v.x); o.y = f2b(v.y); o.z = f2b(v.z); o.w = f2b(v.w);
  ((ushort4*)out)[idx] = o;
}

// ---- transpose + cast (fp32 in): out[n*K + k] = (bf16) in[k*ldin + n] ----
__global__ __launch_bounds__(256) void transpose_cast(const float* __restrict__ in,
                                                      long ldin,
                                                      unsigned short* __restrict__ out,
                                                      int K, int N) {
  __shared__ float t[32][33];
  const int n0 = blockIdx.x * 32, k0 = blockIdx.y * 32;
  const int tx = threadIdx.x, ty = threadIdx.y;
#pragma unroll
  for (int i = 0; i < 4; ++i) {
    int k = k0 + ty + i * 8;
    int n = n0 + tx;
    t[ty + i * 8][tx] = (n < N) ? in[(long)k * ldin + n] : 0.f;
  }
  __syncthreads();
#pragma unroll
  for (int i = 0; i < 4; ++i) {
    int n = n0 + ty + i * 8;
    int k = k0 + tx;
    out[(long)n * K + k] = f2b(t[tx][ty + i * 8]);
  }
}

// ---- RoPE cos/sin table ----
__global__ __launch_bounds__(256) void rope_table(const int* __restrict__ pos,
                                                  float* __restrict__ ct,
                                                  float* __restrict__ st) {
  int tid = blockIdx.x * 256 + threadIdx.x;   // < 2048*32
  int t = tid >> 5, i = tid & 31;
  float p = (float)pos[t];
  float f = p * expf(-(float)i * (11.918390573078392f / 32.f));
  ct[tid] = cosf(f);
  st[tid] = sinf(f);
}

// ---- RoPE + pack q from 3 bf16 partials (pre-scaled by 1/8) ----
__global__ __launch_bounds__(256) void rope_q_pack3(const unsigned short* __restrict__ part,
                                                    const float* __restrict__ ct,
                                                    const float* __restrict__ st,
                                                    unsigned short* __restrict__ qb) {
  int tid = blockIdx.x * 256 + threadIdx.x;   // < 2048*64*32
  int i = tid & 31;
  int h = (tid >> 5) & 63;
  int t = tid >> 11;
  const unsigned short* sp = part + (size_t)t * NQKV + h * 64;
  float x1 = b2f(sp[i]) + b2f(sp[i + (size_t)PART_ELEMS]) + b2f(sp[i + 2 * (size_t)PART_ELEMS]);
  float x2 = b2f(sp[i + 32]) + b2f(sp[i + 32 + (size_t)PART_ELEMS]) + b2f(sp[i + 32 + 2 * (size_t)PART_ELEMS]);
  float c = ct[t * 32 + i], s = st[t * 32 + i];
  int b = t >> 10, sidx = t & 1023;
  unsigned short* dst = qb + (((size_t)(b * NH + h)) * SS + sidx) * HD;
  dst[i]      = f2b((x1 * c - x2 * s) * 0.125f);
  dst[i + 32] = f2b((x1 * s + x2 * c) * 0.125f);
}

// ---- RoPE + pack k from 3 bf16 partials ----
__global__ __launch_bounds__(256) void rope_k_pack3(const unsigned short* __restrict__ part,
                                                    const float* __restrict__ ct,
                                                    const float* __restrict__ st,
                                                    unsigned short* __restrict__ kb) {
  int tid = blockIdx.x * 256 + threadIdx.x;   // < 2048*8*32
  int i = tid & 31;
  int h = (tid >> 5) & 7;
  int t = tid >> 8;
  const unsigned short* sp = part + (size_t)t * NQKV + NQ + h * 64;
  float x1 = b2f(sp[i]) + b2f(sp[i + (size_t)PART_ELEMS]) + b2f(sp[i + 2 * (size_t)PART_ELEMS]);
  float x2 = b2f(sp[i + 32]) + b2f(sp[i + 32 + (size_t)PART_ELEMS]) + b2f(sp[i + 32 + 2 * (size_t)PART_ELEMS]);
  float c = ct[t * 32 + i], s = st[t * 32 + i];
  int b = t >> 10, sidx = t & 1023;
  unsigned short* dst = kb + (((size_t)(b * NKV + h)) * SS + sidx) * HD;
  dst[i]      = f2b(x1 * c - x2 * s);
  dst[i + 32] = f2b(x1 * s + x2 * c);
}

// ---- v pack: transpose + sum3: vtb[b][d][s] = sum_p part[p][b*1024+s][4608+d] ----
__global__ __launch_bounds__(256) void v_pack3(const unsigned short* __restrict__ part,
                                               unsigned short* __restrict__ vtb) {
  __shared__ float t[32][33];
  const int n0 = blockIdx.x * 32;              // d (0..511)
  const int b  = blockIdx.y >> 5;
  const int k0 = (blockIdx.y & 31) * 32;       // s (0..1023)
  const int tx = threadIdx.x, ty = threadIdx.y;
#pragma unroll
  for (int i = 0; i < 4; ++i) {
    int k = k0 + ty + i * 8;
    int n = n0 + tx;
    const unsigned short* sp = part + (size_t)(b * 1024 + k) * NQKV + (NQ + NKVD) + n;
    t[ty + i * 8][tx] = b2f(sp[0]) + b2f(sp[(size_t)PART_ELEMS]) + b2f(sp[2 * (size_t)PART_ELEMS]);
  }
  __syncthreads();
#pragma unroll
  for (int i = 0; i < 4; ++i) {
    int n = n0 + ty + i * 8;
    int k = k0 + tx;
    vtb[((size_t)(b * NKVD + n)) * SS + k] = f2b(t[tx][ty + i * 8]);
  }
}

// ==== GEMM 256x256, BK=64, 8 waves (2Mx4N), m201-style 8-phase schedule ====
// Even K-tiles in buf0, odd in buf1. Per phase: {ds_read quadrant frags ->
// stage 1 half-tile -> s_barrier -> lgkmcnt(0) -> setprio(1) 16 MFMA setprio(0)
// -> [vmcnt at ph4/ph8] -> s_barrier}.
// Stage ledger (per-wave loads, FIFO): prologue 7 half-tiles, vmcnt(6) -> tile0
// landed, 3 half-tiles (6 loads) in flight. Steady: ph1+B1(t+1), ph2+A0(t+2),
// ph3+B0(t+2), ph4+A1(t+2) vmcnt(6) [tile t+1 landed], ph5+B1(t+2),
// ph6..8 +tile(t+3) halves, ph8 vmcnt(6) [tile t+2 landed]. WAR-safe: each
// staged region's last reader phase precedes its staging phase (barriered).
// Tails: gated stages, vmcnt(0) in final pair; odd NT peels last tile.
__global__ __launch_bounds__(512, 2) void gemm256(const unsigned short* __restrict__ A,
                                                  const unsigned short* __restrict__ Bt,
                                                  unsigned short* __restrict__ C0,
                                                  unsigned short* __restrict__ C1,
                                                  unsigned short* __restrict__ C2,
                                                  unsigned short* __restrict__ C3,
                                                  int lda, int Kloop, int ldc, int Nvalid) {
  __shared__ short8 ldsA[2 * 2048];   // 2 bufs x 32KB
  __shared__ short8 ldsB[2 * 2048];
  char* lAc = (char*)ldsA;
  char* lBc = (char*)ldsB;
  const int tid = threadIdx.x;
  const int lane = tid & 63;
  const int w = tid >> 6;
  const int m16 = lane & 15, g4 = lane >> 4;
  const int wr = w >> 2;              // 0..1  (M wave-row)
  const int wc = w & 3;               // 0..3  (N wave-col)
  const int bm = blockIdx.y * 256, bn = blockIdx.x * 256;
  const int z = blockIdx.z;
  unsigned short* __restrict__ Cw = (z == 0) ? C0 : ((z == 1) ? C1 : ((z == 2) ? C2 : C3));
  const size_t strAb = (size_t)lda * 2;            // row stride bytes
  const size_t koffb = (size_t)z * Kloop * 2;      // split-K byte offset
  const char* gAc = (const char*)A;
  const char* gBc = (const char*)Bt;

  // staging: 512 threads x 16B = 8KB; half-tile (128 rows x 128B) = 2 gloads
  const int srow = tid >> 3;                                   // 0..63
  const int scolb = ((tid & 7) * 16) ^ ((srow & 7) << 4);      // inverse-swizzled src col
  const int sdst = w * 1024;                                   // wave-uniform dest

  auto stA = [&](int buf, int half, int kt) {
    const char* src = gAc + (size_t)(bm + half * 128 + srow) * strAb + koffb + (size_t)kt * 128 + scolb;
    char* dst = lAc + buf * 32768 + half * 16384 + sdst;
    gload16(src, dst);
    gload16(src + 64 * strAb, dst + 8192);
  };
  auto stB = [&](int buf, int half, int kt) {
    const char* src = gBc + (size_t)(bn + half * 128 + srow) * strAb + koffb + (size_t)kt * 128 + scolb;
    char* dst = lBc + buf * 32768 + half * 16384 + sdst;
    gload16(src, dst);
    gload16(src + 64 * strAb, dst + 8192);
  };

  // fragment reads (swizzled): global(row, kb) lives at LDS(row, kb ^ ((row&7)<<4))
  const int swz = (m16 & 7) << 4;
  const int kc0 = (g4 * 16) ^ swz;
  const int kc1 = (64 + g4 * 16) ^ swz;

  f32x4 acc[8][4];
#pragma unroll
  for (int i = 0; i < 8; ++i)
#pragma unroll
    for (int j = 0; j < 4; ++j) acc[i][j] = (f32x4){0.f, 0.f, 0.f, 0.f};
  short8 afr[4][2], bf0[2][2], bf1[2][2];

#define LOAD_A(bo, mh) { _Pragma("unroll") for (int mq = 0; mq < 4; ++mq) {                     \
    const int row = (mh) * 128 + wr * 64 + mq * 16 + m16;                                       \
    afr[mq][0] = *(const short8*)(lAc + (bo) + row * 128 + kc0);                                \
    afr[mq][1] = *(const short8*)(lAc + (bo) + row * 128 + kc1); } }
#define LOAD_B(bo, nh, dstf) { _Pragma("unroll") for (int nf = 0; nf < 2; ++nf) {               \
    const int row = (nh) * 128 + wc * 32 + nf * 16 + m16;                                       \
    dstf[nf][0] = *(const short8*)(lBc + (bo) + row * 128 + kc0);                               \
    dstf[nf][1] = *(const short8*)(lBc + (bo) + row * 128 + kc1); } }
#define MFMA_Q(mh, nh, bff) { __builtin_amdgcn_s_setprio(1);                                    \
  _Pragma("unroll") for (int mq = 0; mq < 4; ++mq)                                              \
  _Pragma("unroll") for (int nf = 0; nf < 2; ++nf) {                                            \
    acc[(mh)*4+mq][(nh)*2+nf] = __builtin_amdgcn_mfma_f32_16x16x32_bf16(                        \
        afr[mq][0], bff[nf][0], acc[(mh)*4+mq][(nh)*2+nf], 0, 0, 0);                            \
    acc[(mh)*4+mq][(nh)*2+nf] = __builtin_amdgcn_mfma_f32_16x16x32_bf16(                        \
        afr[mq][1], bff[nf][1], acc[(mh)*4+mq][(nh)*2+nf], 0, 0, 0); }                          \
  __builtin_amdgcn_s_setprio(0); }

  const int NT = Kloop >> 6;   // >= 2 for all uses here
  // prologue: tile0 (A0,B0,A1,B1) + tile1 (A0,B0,A1) = 14 loads; vmcnt(6) -> tile0 landed
  stA(0, 0, 0); stB(0, 0, 0); stA(0, 1, 0); stB(0, 1, 0);
  stA(1, 0, 1); stB(1, 0, 1); stA(1, 1, 1);
  VMC(6);
  BAR();

  for (int t = 0; t + 1 < NT; t += 2) {   // t even: tile t in buf0, t+1 in buf1
    const bool s2 = (t + 2 < NT);
    const bool s3 = (t + 3 < NT);
    // ---- phases 1-4: K-tile t (buf0) ----
    LOAD_A(0, 0); LOAD_B(0, 0, bf0);
    stB(1, 1, t + 1);
    BAR(); LGK0();
    MFMA_Q(0, 0, bf0);
    BAR();

    LOAD_B(0, 1, bf1);
    if (s2) stA(0, 0, t + 2);
    BAR(); LGK0();
    MFMA_Q(0, 1, bf1);
    BAR();

    LOAD_A(0, 1);
    if (s2) stB(0, 0, t + 2);
    BAR(); LGK0();
    MFMA_Q(1, 1, bf1);
    BAR();

    if (s2) stA(0, 1, t + 2);
    BAR();
    MFMA_Q(1, 0, bf0);
    if (s2) { VMC(6); } else { VMC(0); }   // tile t+1 fully landed
    BAR();

    // ---- phases 5-8: K-tile t+1 (buf1) ----
    LOAD_A(32768, 0); LOAD_B(32768, 0, bf0);
    if (s2) stB(0, 1, t + 2);
    BAR(); LGK0();
    MFMA_Q(0, 0, bf0);
    BAR();

    LOAD_B(32768, 1, bf1);
    if (s3) stA(1, 0, t + 3);
    BAR(); LGK0();
    MFMA_Q(0, 1, bf1);
    BAR();

    LOAD_A(32768, 1);
    if (s3) stB(1, 0, t + 3);
    BAR(); LGK0();
    MFMA_Q(1, 1, bf1);
    BAR();

    if (s3) stA(1, 1, t + 3);
    BAR();
    MFMA_Q(1, 0, bf0);
    if (s3) { VMC(6); } else { VMC(0); }   // tile t+2 fully landed
    BAR();
  }
  if (NT & 1) {   // peeled last tile (even index -> buf0); nothing outstanding
    LOAD_A(0, 0); LOAD_B(0, 0, bf0);
    BAR(); LGK0();
    MFMA_Q(0, 0, bf0);
    BAR();
    LOAD_B(0, 1, bf1);
    BAR(); LGK0();
    MFMA_Q(0, 1, bf1);
    BAR();
    LOAD_A(0, 1);
    BAR(); LGK0();
    MFMA_Q(1, 1, bf1);
    BAR();
    MFMA_Q(1, 0, bf0);
  }
#undef LOAD_A
#undef LOAD_B
#undef MFMA_Q

  // epilogue (bf16): row = bm + mh*128 + wr*64 + mq*16 + g4*4 + r ; col = bn + nh*128 + wc*32 + nf*16 + m16
#pragma unroll
  for (int mi = 0; mi < 8; ++mi) {
    const int mh = mi >> 2, mq = mi & 3;
    const size_t row = bm + mh * 128 + wr * 64 + mq * 16 + g4 * 4;
#pragma unroll
    for (int ni = 0; ni < 4; ++ni) {
      const int nh = ni >> 1, nf = ni & 1;
      const int col = bn + nh * 128 + wc * 32 + nf * 16 + m16;
      if (col < Nvalid) {
#pragma unroll
        for (int r = 0; r < 4; ++r)
          Cw[(row + r) * (size_t)ldc + col] = f2b(acc[mi][ni][r]);
      }
    }
  }
}

// ---- split-K reduce: out[2048][2880] fp32 = p0+p1+p2+p3 (bf16 [2048][3072] each) ----
__global__ __launch_bounds__(256) void reduce_wo4(const unsigned short* __restrict__ p0,
                                                  const unsigned short* __restrict__ p1,
                                                  const unsigned short* __restrict__ p2,
                                                  const unsigned short* __restrict__ p3,
                                                  float* __restrict__ out) {
  int idx = blockIdx.x * 256 + threadIdx.x;   // < 2048*720
  int row = idx / 720, c4 = idx - row * 720;
  const size_t o = (size_t)row * 3072 + c4 * 4;
  const ushort4 a = *(const ushort4*)(p0 + o);
  const ushort4 b = *(const ushort4*)(p1 + o);
  const ushort4 c = *(const ushort4*)(p2 + o);
  const ushort4 d = *(const ushort4*)(p3 + o);
  float4 r;
  r.x = (b2f(a.x) + b2f(b.x)) + (b2f(c.x) + b2f(d.x));
  r.y = (b2f(a.y) + b2f(b.y)) + (b2f(c.y) + b2f(d.y));
  r.z = (b2f(a.z) + b2f(b.z)) + (b2f(c.z) + b2f(d.z));
  r.w = (b2f(a.w) + b2f(b.w)) + (b2f(c.w) + b2f(d.w));
  *(float4*)(out + (size_t)row * 2880 + c4 * 4) = r;
}

// ---- flash attention (unchanged, validated R2-R8) ----
__global__ __launch_bounds__(512) void attn_fwd(const unsigned short* __restrict__ qb,
                                                const unsigned short* __restrict__ kb,
                                                const unsigned short* __restrict__ vtb,
                                                unsigned short* __restrict__ ao) {
  __shared__ unsigned short kB[2][64 * 64];
  __shared__ unsigned short vB[2][64 * 64];
  __shared__ unsigned short pB[8][32 * 64];
  const int tid = threadIdx.x, lane = tid & 63, w = tid >> 6;
  const int qblk = blockIdx.x;
  const int bh = blockIdx.y;
  const int b = bh >> 6, h = bh & 63, hkv = h >> 3;
  const int m16 = lane & 15, g4 = lane >> 4;
  const int rbase = qblk * 256 + w * 32;

  const unsigned short* qp =
      qb + (((size_t)(b * NH + h)) * SS + rbase + m16) * HD + g4 * 8;
  const short8 q00 = *(const short8*)(qp);
  const short8 q01 = *(const short8*)(qp + 32);
  const short8 q10 = *(const short8*)(qp + 16 * HD);
  const short8 q11 = *(const short8*)(qp + 16 * HD + 32);

  const char* kbp = (const char*)(kb + ((size_t)(b * NKV + hkv)) * SS * HD);
  const char* vbp = (const char*)(vtb + ((size_t)(b * NKV + hkv)) * HD * SS);

  const int lrow = lane >> 3;
  const int lcolb = ((lane & 7) * 16) ^ ((lrow & 7) << 4);
  unsigned short* kDst0 = &kB[0][w * 512];
  unsigned short* kDst1 = &kB[1][w * 512];
  unsigned short* vDst0 = &vB[0][w * 512];
  unsigned short* vDst1 = &vB[1][w * 512];
  const size_t kRowOff = (size_t)(w * 8 + lrow) * 128 + lcolb;
  const size_t vRowOff = (size_t)(w * 8 + lrow) * 2048 + lcolb;

  const short8 ones = {(short)0x3F80, (short)0x3F80, (short)0x3F80, (short)0x3F80,
                       (short)0x3F80, (short)0x3F80, (short)0x3F80, (short)0x3F80};

  f32x4 o0[4], o1[4];
#pragma unroll
  for (int n = 0; n < 4; ++n) { o0[n] = (f32x4){0,0,0,0}; o1[n] = (f32x4){0,0,0,0}; }
  f32x4 lacc0 = (f32x4){0,0,0,0}, lacc1 = (f32x4){0,0,0,0};
  float mrow0[4] = {-1e30f,-1e30f,-1e30f,-1e30f};
  float mrow1[4] = {-1e30f,-1e30f,-1e30f,-1e30f};

  char* pw = (char*)pB[w];
  const int swz_m = (m16 & 7) << 4;
  const int nt = (qblk + 1) * 4;

  gload16(kbp + kRowOff, kDst0);
  gload16(vbp + vRowOff, vDst0);
  __syncthreads();

  for (int t = 0; t < nt; ++t) {
    const int k0 = t * 64;
    const char* kLds = (const char*)kB[t & 1];
    const char* vLds = (const char*)vB[t & 1];
    if (t + 1 < nt) {
      if (t & 1) { gload16(kbp + (size_t)(t + 1) * 8192 + kRowOff, kDst0);
                   gload16(vbp + (size_t)(t + 1) * 128  + vRowOff, vDst0); }
      else       { gload16(kbp + (size_t)(t + 1) * 8192 + kRowOff, kDst1);
                   gload16(vbp + (size_t)(t + 1) * 128  + vRowOff, vDst1); }
    }
    if (k0 < rbase + 32) {
      short8 kf0[4], kf1[4];
#pragma unroll
      for (int kf = 0; kf < 4; ++kf) {
        const int rb = (kf * 16 + m16) * 128;
        kf0[kf] = *(const short8*)(kLds + ((rb + g4 * 16) ^ swz_m));
        kf1[kf] = *(const short8*)(kLds + ((rb + 64 + g4 * 16) ^ swz_m));
      }
      f32x4 s0[4], s1[4];
      __builtin_amdgcn_s_setprio(1);
#pragma unroll
      for (int kf = 0; kf < 4; ++kf) {
        f32x4 z = (f32x4){0,0,0,0};
        z = __builtin_amdgcn_mfma_f32_16x16x32_bf16(q00, kf0[kf], z, 0, 0, 0);
        z = __builtin_amdgcn_mfma_f32_16x16x32_bf16(q01, kf1[kf], z, 0, 0, 0);
        s0[kf] = z;
        f32x4 z2 = (f32x4){0,0,0,0};
        z2 = __builtin_amdgcn_mfma_f32_16x16x32_bf16(q10, kf0[kf], z2, 0, 0, 0);
        z2 = __builtin_amdgcn_mfma_f32_16x16x32_bf16(q11, kf1[kf], z2, 0, 0, 0);
        s1[kf] = z2;
      }
      __builtin_amdgcn_s_setprio(0);
      if (k0 + 63 >= rbase) {
#pragma unroll
        for (int kf = 0; kf < 4; ++kf)
#pragma unroll
          for (int r = 0; r < 4; ++r) {
            const int col = k0 + kf * 16 + m16;
            if (col > rbase + g4 * 4 + r)      s0[kf][r] = -1e30f;
            if (col > rbase + 16 + g4 * 4 + r) s1[kf][r] = -1e30f;
          }
      }
      int grow = 0;
#pragma unroll
      for (int kf = 0; kf < 4; ++kf)
#pragma unroll
        for (int r = 0; r < 4; ++r) {
          grow |= (s0[kf][r] > mrow0[r] + 8.f);
          grow |= (s1[kf][r] > mrow1[r] + 8.f);
        }
      if (__any(grow)) {
        float mx0[4], mx1[4];
#pragma unroll
        for (int r = 0; r < 4; ++r) {
          mx0[r] = fmaxf(fmaxf(s0[0][r], s0[1][r]), fmaxf(s0[2][r], s0[3][r]));
          mx1[r] = fmaxf(fmaxf(s1[0][r], s1[1][r]), fmaxf(s1[2][r], s1[3][r]));
        }
#pragma unroll
        for (int off = 1; off <= 8; off <<= 1)
#pragma unroll
          for (int r = 0; r < 4; ++r) {
            mx0[r] = fmaxf(mx0[r], __shfl_xor(mx0[r], off));
            mx1[r] = fmaxf(mx1[r], __shfl_xor(mx1[r], off));
          }
#pragma unroll
        for (int r = 0; r < 4; ++r) {
          float mn0 = fmaxf(mrow0[r], mx0[r]);
          float sc0 = __expf(mrow0[r] - mn0);
          mrow0[r] = mn0; lacc0[r] *= sc0;
          float mn1 = fmaxf(mrow1[r], mx1[r]);
          float sc1 = __expf(mrow1[r] - mn1);
          mrow1[r] = mn1; lacc1[r] *= sc1;
#pragma unroll
          for (int n = 0; n < 4; ++n) { o0[n][r] *= sc0; o1[n][r] *= sc1; }
        }
      }
#pragma unroll
      for (int kf = 0; kf < 4; ++kf)
#pragma unroll
        for (int r = 0; r < 4; ++r) {
          const int colb = (kf * 16 + m16) * 2;
          int row = g4 * 4 + r;
          *(unsigned short*)(pw + ((row * 128 + colb) ^ ((row & 7) << 4))) =
              f2b(__expf(s0[kf][r] - mrow0[r]));
          row += 16;
          *(unsigned short*)(pw + ((row * 128 + colb) ^ ((row & 7) << 4))) =
              f2b(__expf(s1[kf][r] - mrow1[r]));
        }
      const int prb0 = m16 * 128, prb1 = (16 + m16) * 128;
      short8 pf00 = *(const short8*)(pw + ((prb0 + g4 * 16) ^ swz_m));
      short8 pf01 = *(const short8*)(pw + ((prb0 + 64 + g4 * 16) ^ swz_m));
      short8 pf10 = *(const short8*)(pw + ((prb1 + g4 * 16) ^ swz_m));
      short8 pf11 = *(const short8*)(pw + ((prb1 + 64 + g4 * 16) ^ swz_m));
      __builtin_amdgcn_s_setprio(1);
      lacc0 = __builtin_amdgcn_mfma_f32_16x16x32_bf16(pf00, ones, lacc0, 0, 0, 0);
      lacc0 = __builtin_amdgcn_mfma_f32_16x16x32_bf16(pf01, ones, lacc0, 0, 0, 0);
      lacc1 = __builtin_amdgcn_mfma_f32_16x16x32_bf16(pf10, ones, lacc1, 0, 0, 0);
      lacc1 = __builtin_amdgcn_mfma_f32_16x16x32_bf16(pf11, ones, lacc1, 0, 0, 0);
#pragma unroll
      for (int n = 0; n < 4; ++n) {
        const int rb = (n * 16 + m16) * 128;
        short8 vf0 = *(const short8*)(vLds + ((rb + g4 * 16) ^ swz_m));
        short8 vf1 = *(const short8*)(vLds + ((rb + 64 + g4 * 16) ^ swz_m));
        o0[n] = __builtin_amdgcn_mfma_f32_16x16x32_bf16(pf00, vf0, o0[n], 0, 0, 0);
        o0[n] = __builtin_amdgcn_mfma_f32_16x16x32_bf16(pf01, vf1, o0[n], 0, 0, 0);
        o1[n] = __builtin_amdgcn_mfma_f32_16x16x32_bf16(pf10, vf0, o1[n], 0, 0, 0);
        o1[n] = __builtin_amdgcn_mfma_f32_16x16x32_bf16(pf11, vf1, o1[n], 0, 0, 0);
      }
      __builtin_amdgcn_s_setprio(0);
    }
    __syncthreads();
  }

  float inv0[4], inv1[4];
#pragma unroll
  for (int r = 0; r < 4; ++r) { inv0[r] = 1.f / lacc0[r]; inv1[r] = 1.f / lacc1[r]; }
  const size_t row0 = (size_t)b * SS + rbase + g4 * 4;
#pragma unroll
  for (int n = 0; n < 4; ++n)
#pragma unroll
    for (int r = 0; r < 4; ++r) {
      ao[(row0 + r) * (size_t)NQ + h * 64 + n * 16 + m16] = f2b(o0[n][r] * inv0[r]);
      ao[(row0 + 16 + r) * (size_t)NQ + h * 64 + n * 16 + m16] = f2b(o1[n][r] * inv1[r]);
    }
}

// ---- workspace layout (bytes) ----
constexpr size_t OFF_XB    = 0;
constexpr size_t OFF_WQKVT = 11796480;
constexpr size_t OFF_PART  = 41287680;
constexpr size_t OFF_WOT   = 0;
constexpr size_t OFF_P1    = 25165824;
constexpr size_t OFF_ATTNB = 41287680;
constexpr size_t OFF_P0    = 58064896;
constexpr size_t OFF_P2    = 70647808;
constexpr size_t OFF_P3    = 83230720;
constexpr size_t OFF_CT    = 104202240;
constexpr size_t OFF_ST    = 104464384;
constexpr size_t OFF_QB    = 104726528;
constexpr size_t OFF_KB    = 121503744;
constexpr size_t OFF_VTB   = 123600896;

extern "C" void kernel_launch(void* const* d_in, const int* in_sizes, int n_in,
                              void* d_out, int out_size, void* d_ws, size_t ws_size,
                              hipStream_t stream) {
  const float* x  = (const float*)d_in[0];
  const float* wq = (const float*)d_in[1];
  const float* wk = (const float*)d_in[2];
  const float* wv = (const float*)d_in[3];
  const float* wo = (const float*)d_in[4];
  const int* pos  = (const int*)d_in[5];
  float* out = (float*)d_out;
  char* ws = (char*)d_ws;

  unsigned short* xb    = (unsigned short*)(ws + OFF_XB);
  unsigned short* wqkvt = (unsigned short*)(ws + OFF_WQKVT);
  unsigned short* part  = (unsigned short*)(ws + OFF_PART);
  unsigned short* wot   = (unsigned short*)(ws + OFF_WOT);
  unsigned short* p0    = (unsigned short*)(ws + OFF_P0);
  unsigned short* p1    = (unsigned short*)(ws + OFF_P1);
  unsigned short* p2    = (unsigned short*)(ws + OFF_P2);
  unsigned short* p3    = (unsigned short*)(ws + OFF_P3);
  unsigned short* attnb = (unsigned short*)(ws + OFF_ATTNB);
  float* ct             = (float*)(ws + OFF_CT);
  float* st             = (float*)(ws + OFF_ST);
  unsigned short* qbuf  = (unsigned short*)(ws + OFF_QB);
  unsigned short* kbuf  = (unsigned short*)(ws + OFF_KB);
  unsigned short* vtb   = (unsigned short*)(ws + OFF_VTB);

  cast_x_kernel<<<(M_TOK * HIDDEN / 4 + 255) / 256, 256, 0, stream>>>(x, xb, M_TOK * HIDDEN / 4);
  rope_table<<<(M_TOK * 32) / 256, 256, 0, stream>>>(pos, ct, st);
  transpose_cast<<<dim3(NQ / 32, HIDDEN / 32), dim3(32, 8), 0, stream>>>(
      wq, NQ, wqkvt, HIDDEN, NQ);
  transpose_cast<<<dim3(NKVD / 32, HIDDEN / 32), dim3(32, 8), 0, stream>>>(
      wk, NKVD, wqkvt + (size_t)NQ * HIDDEN, HIDDEN, NKVD);
  transpose_cast<<<dim3(NKVD / 32, HIDDEN / 32), dim3(32, 8), 0, stream>>>(
      wv, NKVD, wqkvt + (size_t)(NQ + NKVD) * HIDDEN, HIDDEN, NKVD);
  // QKV projection: split-K=3 (K=3x960, NT=15), grid 20x8x3 = 480 blocks
  gemm256<<<dim3(NQKV / 256, M_TOK / 256, 3), 512, 0, stream>>>(
      xb, wqkvt, part, part + (size_t)PART_ELEMS, part + 2 * (size_t)PART_ELEMS, nullptr,
      HIDDEN, HIDDEN / 3, NQKV, NQKV);
  // wo transpose into region A (xb/wqkvt now dead)
  transpose_cast<<<dim3(NOUT_PAD / 32, NQ / 32), dim3(32, 8), 0, stream>>>(
      wo, NOUT, wot, NQ, NOUT);
  // RoPE + pack (sums the 3 partials)
  rope_q_pack3<<<(M_TOK * NH * 32) / 256, 256, 0, stream>>>(part, ct, st, qbuf);
  rope_k_pack3<<<(M_TOK * NKV * 32) / 256, 256, 0, stream>>>(part, ct, st, kbuf);
  v_pack3<<<dim3(NKVD / 32, BB * 32), dim3(32, 8), 0, stream>>>(part, vtb);
  // attention (partials dead; attnb overlays part[0])
  attn_fwd<<<dim3(4, BB * NH), 512, 0, stream>>>(qbuf, kbuf, vtb, attnb);
  // output projection: split-K=4 (K=4x1024, NT=16), grid 12x8x4 = 384 blocks
  gemm256<<<dim3(NOUT_PAD / 256, M_TOK / 256, 4), 512, 0, stream>>>(
      attnb, wot, p0, p1, p2, p3, NQ, NQ / 4, NOUT_PAD, NOUT_PAD);
  reduce_wo4<<<(M_TOK * 720) / 256, 256, 0, stream>>>(p0, p1, p2, p3, out);
}

// Round 10
// 271.273 us; speedup vs baseline: 1.1095x; 1.1020x over previous
//
#include <hip/hip_runtime.h>

// ---- problem constants ----
#define BB 2
#define SS 1024
#define HIDDEN 2880
#define NH 64
#define NKV 8
#define HD 64
#define M_TOK 2048          // B*S
#define NQ 4096             // NH*HD
#define NKVD 512            // NKV*HD
#define NQKV 5120           // NQ + 2*NKVD
#define NOUT 2880
#define NOUT_PAD 2944       // 23*128

typedef __attribute__((ext_vector_type(8))) short short8;
typedef __attribute__((ext_vector_type(4))) float f32x4;

__device__ __forceinline__ unsigned short f2b(float x) {
  union { float f; unsigned u; } v; v.f = x;
  unsigned r = (v.u + 0x7FFFu + ((v.u >> 16) & 1u)) >> 16;
  return (unsigned short)r;
}

__device__ __forceinline__ void gload16(const void* g, void* l) {
  __builtin_amdgcn_global_load_lds(
      (const __attribute__((address_space(1))) void*)g,
      (__attribute__((address_space(3))) void*)l, 16, 0, 0);
}

// ---- cast x (fp32 -> bf16), vectorized ----
__global__ __launch_bounds__(256) void cast_x_kernel(const float* __restrict__ in,
                                                     unsigned short* __restrict__ out,
                                                     int n4) {
  int idx = blockIdx.x * 256 + threadIdx.x;
  if (idx >= n4) return;
  float4 v = ((const float4*)in)[idx];
  ushort4 o;
  o.x = f2b(v.x); o.y = f2b(v.y); o.z = f2b(v.z); o.w = f2b(v.w);
  ((ushort4*)out)[idx] = o;
}

// ---- transpose + cast (fp32 in): out[n*K + k] = (bf16) in[k*ldin + n] ----
__global__ __launch_bounds__(256) void transpose_cast(const float* __restrict__ in,
                                                      long ldin,
                                                      unsigned short* __restrict__ out,
                                                      int K, int N) {
  __shared__ float t[32][33];
  const int n0 = blockIdx.x * 32, k0 = blockIdx.y * 32;
  const int tx = threadIdx.x, ty = threadIdx.y;
#pragma unroll
  for (int i = 0; i < 4; ++i) {
    int k = k0 + ty + i * 8;
    int n = n0 + tx;
    t[ty + i * 8][tx] = (n < N) ? in[(long)k * ldin + n] : 0.f;
  }
  __syncthreads();
#pragma unroll
  for (int i = 0; i < 4; ++i) {
    int n = n0 + ty + i * 8;
    int k = k0 + tx;
    out[(long)n * K + k] = f2b(t[tx][ty + i * 8]);
  }
}

// ---- RoPE cos/sin table ----
__global__ __launch_bounds__(256) void rope_table(const int* __restrict__ pos,
                                                  float* __restrict__ ct,
                                                  float* __restrict__ st) {
  int tid = blockIdx.x * 256 + threadIdx.x;   // < 2048*32
  int t = tid >> 5, i = tid & 31;
  float p = (float)pos[t];
  float f = p * expf(-(float)i * (11.918390573078392f / 32.f));
  ct[tid] = cosf(f);
  st[tid] = sinf(f);
}

// ---- RoPE + pack q (fp32 qkvf, pre-scaled by 1/8) ----
__global__ __launch_bounds__(256) void rope_q_pack(const float* __restrict__ qkvf,
                                                   const float* __restrict__ ct,
                                                   const float* __restrict__ st,
                                                   unsigned short* __restrict__ qb) {
  int tid = blockIdx.x * 256 + threadIdx.x;   // < 2048*64*32
  int i = tid & 31;
  int h = (tid >> 5) & 63;
  int t = tid >> 11;
  const float* src = qkvf + (size_t)t * NQKV + h * 64;
  float x1 = src[i], x2 = src[i + 32];
  float c = ct[t * 32 + i], s = st[t * 32 + i];
  int b = t >> 10, sidx = t & 1023;
  unsigned short* dst = qb + (((size_t)(b * NH + h)) * SS + sidx) * HD;
  dst[i]      = f2b((x1 * c - x2 * s) * 0.125f);
  dst[i + 32] = f2b((x1 * s + x2 * c) * 0.125f);
}

// ---- RoPE + pack k ----
__global__ __launch_bounds__(256) void rope_k_pack(const float* __restrict__ qkvf,
                                                   const float* __restrict__ ct,
                                                   const float* __restrict__ st,
                                                   unsigned short* __restrict__ kb) {
  int tid = blockIdx.x * 256 + threadIdx.x;   // < 2048*8*32
  int i = tid & 31;
  int h = (tid >> 5) & 7;
  int t = tid >> 8;
  const float* src = qkvf + (size_t)t * NQKV + NQ + h * 64;
  float x1 = src[i], x2 = src[i + 32];
  float c = ct[t * 32 + i], s = st[t * 32 + i];
  int b = t >> 10, sidx = t & 1023;
  unsigned short* dst = kb + (((size_t)(b * NKV + h)) * SS + sidx) * HD;
  dst[i]      = f2b(x1 * c - x2 * s);
  dst[i + 32] = f2b(x1 * s + x2 * c);
}

// ==== GEMM 128x128, BK=64, 4 waves (2x2), single-buffer m97 structure ====
// C(fp32)[M][ldc] = A_bf16[M][lda] x Bt_bf16[N][lda]^T.  lda%64==0.
// LDS 32KB (A 16K + B 16K) -> ~3 blocks/CU resident (VGPR-bound at 3 waves/EU);
// TLP across blocks hides the per-tile stage drain (m97/m114 regime).
// XOR swizzle (validated): LDS(row,c) = global(row, c ^ ((row&7)<<4));
// ds_read lanes land 2 lanes/bank = conflict-free.
__global__ __launch_bounds__(256, 3) void gemm128(const unsigned short* __restrict__ A,
                                                  const unsigned short* __restrict__ Bt,
                                                  float* __restrict__ C,
                                                  int lda, int ldc, int Nvalid) {
  __shared__ char lA[128 * 128];   // [128 rows][128 bytes]
  __shared__ char lB[128 * 128];
  const int tid = threadIdx.x;
  const int lane = tid & 63;
  const int w = tid >> 6;
  const int m16 = lane & 15, g4 = lane >> 4;
  const int wr = w >> 1, wc = w & 1;          // 2x2 waves, each 64x64 output
  const int bm = blockIdx.y * 128, bn = blockIdx.x * 128;
  const size_t strb = (size_t)lda * 2;        // row stride bytes

  // staging: 256 threads x 16B = 4KB/issue = 32 rows x 128B; 4 issues per matrix
  const int srow = tid >> 3;                                   // 0..31
  const int scolb = ((tid & 7) * 16) ^ ((srow & 7) << 4);      // inverse-swizzled src col
  const int sdst = w * 1024;                                   // wave-uniform dest
  const char* ga0 = (const char*)A + (size_t)(bm + srow) * strb + scolb;
  const char* gb0 = (const char*)Bt + (size_t)(bn + srow) * strb + scolb;

  // fragment read cols (swizzled)
  const int swz = (m16 & 7) << 4;
  const int kc0 = (g4 * 16) ^ swz;
  const int kc1 = (64 + g4 * 16) ^ swz;

  f32x4 acc[4][4];
#pragma unroll
  for (int i = 0; i < 4; ++i)
#pragma unroll
    for (int j = 0; j < 4; ++j) acc[i][j] = (f32x4){0.f, 0.f, 0.f, 0.f};

  const int NT = lda >> 6;
  for (int t = 0; t < NT; ++t) {
    const size_t ko = (size_t)t * 128;
    __syncthreads();   // all reads of previous tile done before overwrite
#pragma unroll
    for (int i = 0; i < 4; ++i) {
      gload16(ga0 + (size_t)(i * 32) * strb + ko, lA + i * 4096 + sdst);
      gload16(gb0 + (size_t)(i * 32) * strb + ko, lB + i * 4096 + sdst);
    }
    __syncthreads();   // compiler emits vmcnt(0) drain before barrier (m97 pattern)
    short8 af[4][2], bf[4][2];
#pragma unroll
    for (int mq = 0; mq < 4; ++mq) {
      const int row = wr * 64 + mq * 16 + m16;
      af[mq][0] = *(const short8*)(lA + row * 128 + kc0);
      af[mq][1] = *(const short8*)(lA + row * 128 + kc1);
    }
#pragma unroll
    for (int nf = 0; nf < 4; ++nf) {
      const int row = wc * 64 + nf * 16 + m16;
      bf[nf][0] = *(const short8*)(lB + row * 128 + kc0);
      bf[nf][1] = *(const short8*)(lB + row * 128 + kc1);
    }
    __builtin_amdgcn_s_setprio(1);
#pragma unroll
    for (int mq = 0; mq < 4; ++mq)
#pragma unroll
      for (int nf = 0; nf < 4; ++nf) {
        acc[mq][nf] = __builtin_amdgcn_mfma_f32_16x16x32_bf16(af[mq][0], bf[nf][0], acc[mq][nf], 0, 0, 0);
        acc[mq][nf] = __builtin_amdgcn_mfma_f32_16x16x32_bf16(af[mq][1], bf[nf][1], acc[mq][nf], 0, 0, 0);
      }
    __builtin_amdgcn_s_setprio(0);
  }

  // epilogue fp32: row = bm + wr*64 + mq*16 + g4*4 + r ; col = bn + wc*64 + nf*16 + m16
#pragma unroll
  for (int mq = 0; mq < 4; ++mq) {
    const size_t row = bm + wr * 64 + mq * 16 + g4 * 4;
#pragma unroll
    for (int nf = 0; nf < 4; ++nf) {
      const int col = bn + wc * 64 + nf * 16 + m16;
      if (col < Nvalid) {
#pragma unroll
        for (int r = 0; r < 4; ++r)
          C[(row + r) * (size_t)ldc + col] = acc[mq][nf][r];
      }
    }
  }
}

// ---- flash attention (unchanged, validated R2-R9) ----
__global__ __launch_bounds__(512) void attn_fwd(const unsigned short* __restrict__ qb,
                                                const unsigned short* __restrict__ kb,
                                                const unsigned short* __restrict__ vtb,
                                                unsigned short* __restrict__ ao) {
  __shared__ unsigned short kB[2][64 * 64];
  __shared__ unsigned short vB[2][64 * 64];
  __shared__ unsigned short pB[8][32 * 64];
  const int tid = threadIdx.x, lane = tid & 63, w = tid >> 6;
  const int qblk = blockIdx.x;
  const int bh = blockIdx.y;
  const int b = bh >> 6, h = bh & 63, hkv = h >> 3;
  const int m16 = lane & 15, g4 = lane >> 4;
  const int rbase = qblk * 256 + w * 32;

  const unsigned short* qp =
      qb + (((size_t)(b * NH + h)) * SS + rbase + m16) * HD + g4 * 8;
  const short8 q00 = *(const short8*)(qp);
  const short8 q01 = *(const short8*)(qp + 32);
  const short8 q10 = *(const short8*)(qp + 16 * HD);
  const short8 q11 = *(const short8*)(qp + 16 * HD + 32);

  const char* kbp = (const char*)(kb + ((size_t)(b * NKV + hkv)) * SS * HD);
  const char* vbp = (const char*)(vtb + ((size_t)(b * NKV + hkv)) * HD * SS);

  const int lrow = lane >> 3;
  const int lcolb = ((lane & 7) * 16) ^ ((lrow & 7) << 4);
  unsigned short* kDst0 = &kB[0][w * 512];
  unsigned short* kDst1 = &kB[1][w * 512];
  unsigned short* vDst0 = &vB[0][w * 512];
  unsigned short* vDst1 = &vB[1][w * 512];
  const size_t kRowOff = (size_t)(w * 8 + lrow) * 128 + lcolb;
  const size_t vRowOff = (size_t)(w * 8 + lrow) * 2048 + lcolb;

  const short8 ones = {(short)0x3F80, (short)0x3F80, (short)0x3F80, (short)0x3F80,
                       (short)0x3F80, (short)0x3F80, (short)0x3F80, (short)0x3F80};

  f32x4 o0[4], o1[4];
#pragma unroll
  for (int n = 0; n < 4; ++n) { o0[n] = (f32x4){0,0,0,0}; o1[n] = (f32x4){0,0,0,0}; }
  f32x4 lacc0 = (f32x4){0,0,0,0}, lacc1 = (f32x4){0,0,0,0};
  float mrow0[4] = {-1e30f,-1e30f,-1e30f,-1e30f};
  float mrow1[4] = {-1e30f,-1e30f,-1e30f,-1e30f};

  char* pw = (char*)pB[w];
  const int swz_m = (m16 & 7) << 4;
  const int nt = (qblk + 1) * 4;

  gload16(kbp + kRowOff, kDst0);
  gload16(vbp + vRowOff, vDst0);
  __syncthreads();

  for (int t = 0; t < nt; ++t) {
    const int k0 = t * 64;
    const char* kLds = (const char*)kB[t & 1];
    const char* vLds = (const char*)vB[t & 1];
    if (t + 1 < nt) {
      if (t & 1) { gload16(kbp + (size_t)(t + 1) * 8192 + kRowOff, kDst0);
                   gload16(vbp + (size_t)(t + 1) * 128  + vRowOff, vDst0); }
      else       { gload16(kbp + (size_t)(t + 1) * 8192 + kRowOff, kDst1);
                   gload16(vbp + (size_t)(t + 1) * 128  + vRowOff, vDst1); }
    }
    if (k0 < rbase + 32) {
      short8 kf0[4], kf1[4];
#pragma unroll
      for (int kf = 0; kf < 4; ++kf) {
        const int rb = (kf * 16 + m16) * 128;
        kf0[kf] = *(const short8*)(kLds + ((rb + g4 * 16) ^ swz_m));
        kf1[kf] = *(const short8*)(kLds + ((rb + 64 + g4 * 16) ^ swz_m));
      }
      f32x4 s0[4], s1[4];
      __builtin_amdgcn_s_setprio(1);
#pragma unroll
      for (int kf = 0; kf < 4; ++kf) {
        f32x4 z = (f32x4){0,0,0,0};
        z = __builtin_amdgcn_mfma_f32_16x16x32_bf16(q00, kf0[kf], z, 0, 0, 0);
        z = __builtin_amdgcn_mfma_f32_16x16x32_bf16(q01, kf1[kf], z, 0, 0, 0);
        s0[kf] = z;
        f32x4 z2 = (f32x4){0,0,0,0};
        z2 = __builtin_amdgcn_mfma_f32_16x16x32_bf16(q10, kf0[kf], z2, 0, 0, 0);
        z2 = __builtin_amdgcn_mfma_f32_16x16x32_bf16(q11, kf1[kf], z2, 0, 0, 0);
        s1[kf] = z2;
      }
      __builtin_amdgcn_s_setprio(0);
      if (k0 + 63 >= rbase) {
#pragma unroll
        for (int kf = 0; kf < 4; ++kf)
#pragma unroll
          for (int r = 0; r < 4; ++r) {
            const int col = k0 + kf * 16 + m16;
            if (col > rbase + g4 * 4 + r)      s0[kf][r] = -1e30f;
            if (col > rbase + 16 + g4 * 4 + r) s1[kf][r] = -1e30f;
          }
      }
      int grow = 0;
#pragma unroll
      for (int kf = 0; kf < 4; ++kf)
#pragma unroll
        for (int r = 0; r < 4; ++r) {
          grow |= (s0[kf][r] > mrow0[r] + 8.f);
          grow |= (s1[kf][r] > mrow1[r] + 8.f);
        }
      if (__any(grow)) {
        float mx0[4], mx1[4];
#pragma unroll
        for (int r = 0; r < 4; ++r) {
          mx0[r] = fmaxf(fmaxf(s0[0][r], s0[1][r]), fmaxf(s0[2][r], s0[3][r]));
          mx1[r] = fmaxf(fmaxf(s1[0][r], s1[1][r]), fmaxf(s1[2][r], s1[3][r]));
        }
#pragma unroll
        for (int off = 1; off <= 8; off <<= 1)
#pragma unroll
          for (int r = 0; r < 4; ++r) {
            mx0[r] = fmaxf(mx0[r], __shfl_xor(mx0[r], off));
            mx1[r] = fmaxf(mx1[r], __shfl_xor(mx1[r], off));
          }
#pragma unroll
        for (int r = 0; r < 4; ++r) {
          float mn0 = fmaxf(mrow0[r], mx0[r]);
          float sc0 = __expf(mrow0[r] - mn0);
          mrow0[r] = mn0; lacc0[r] *= sc0;
          float mn1 = fmaxf(mrow1[r], mx1[r]);
          float sc1 = __expf(mrow1[r] - mn1);
          mrow1[r] = mn1; lacc1[r] *= sc1;
#pragma unroll
          for (int n = 0; n < 4; ++n) { o0[n][r] *= sc0; o1[n][r] *= sc1; }
        }
      }
#pragma unroll
      for (int kf = 0; kf < 4; ++kf)
#pragma unroll
        for (int r = 0; r < 4; ++r) {
          const int colb = (kf * 16 + m16) * 2;
          int row = g4 * 4 + r;
          *(unsigned short*)(pw + ((row * 128 + colb) ^ ((row & 7) << 4))) =
              f2b(__expf(s0[kf][r] - mrow0[r]));
          row += 16;
          *(unsigned short*)(pw + ((row * 128 + colb) ^ ((row & 7) << 4))) =
              f2b(__expf(s1[kf][r] - mrow1[r]));
        }
      const int prb0 = m16 * 128, prb1 = (16 + m16) * 128;
      short8 pf00 = *(const short8*)(pw + ((prb0 + g4 * 16) ^ swz_m));
      short8 pf01 = *(const short8*)(pw + ((prb0 + 64 + g4 * 16) ^ swz_m));
      short8 pf10 = *(const short8*)(pw + ((prb1 + g4 * 16) ^ swz_m));
      short8 pf11 = *(const short8*)(pw + ((prb1 + 64 + g4 * 16) ^ swz_m));
      __builtin_amdgcn_s_setprio(1);
      lacc0 = __builtin_amdgcn_mfma_f32_16x16x32_bf16(pf00, ones, lacc0, 0, 0, 0);
      lacc0 = __builtin_amdgcn_mfma_f32_16x16x32_bf16(pf01, ones, lacc0, 0, 0, 0);
      lacc1 = __builtin_amdgcn_mfma_f32_16x16x32_bf16(pf10, ones, lacc1, 0, 0, 0);
      lacc1 = __builtin_amdgcn_mfma_f32_16x16x32_bf16(pf11, ones, lacc1, 0, 0, 0);
#pragma unroll
      for (int n = 0; n < 4; ++n) {
        const int rb = (n * 16 + m16) * 128;
        short8 vf0 = *(const short8*)(vLds + ((rb + g4 * 16) ^ swz_m));
        short8 vf1 = *(const short8*)(vLds + ((rb + 64 + g4 * 16) ^ swz_m));
        o0[n] = __builtin_amdgcn_mfma_f32_16x16x32_bf16(pf00, vf0, o0[n], 0, 0, 0);
        o0[n] = __builtin_amdgcn_mfma_f32_16x16x32_bf16(pf01, vf1, o0[n], 0, 0, 0);
        o1[n] = __builtin_amdgcn_mfma_f32_16x16x32_bf16(pf10, vf0, o1[n], 0, 0, 0);
        o1[n] = __builtin_amdgcn_mfma_f32_16x16x32_bf16(pf11, vf1, o1[n], 0, 0, 0);
      }
      __builtin_amdgcn_s_setprio(0);
    }
    __syncthreads();
  }

  float inv0[4], inv1[4];
#pragma unroll
  for (int r = 0; r < 4; ++r) { inv0[r] = 1.f / lacc0[r]; inv1[r] = 1.f / lacc1[r]; }
  const size_t row0 = (size_t)b * SS + rbase + g4 * 4;
#pragma unroll
  for (int n = 0; n < 4; ++n)
#pragma unroll
    for (int r = 0; r < 4; ++r) {
      ao[(row0 + r) * (size_t)NQ + h * 64 + n * 16 + m16] = f2b(o0[n][r] * inv0[r]);
      ao[(row0 + 16 + r) * (size_t)NQ + h * 64 + n * 16 + m16] = f2b(o1[n][r] * inv1[r]);
    }
}

// ---- workspace layout (bytes), total 128,843,776 (R1-proven size) ----
constexpr size_t OFF_XB    = 0;                          // 11,796,480
constexpr size_t OFF_WQKVT = 11796480;                   // 29,491,200
constexpr size_t OFF_WOT   = 41287680;                   // 2944*4096*2 = 24,117,248
constexpr size_t OFF_COS   = 65404928;                   // 262,144
constexpr size_t OFF_SIN   = 65667072;                   // 262,144
constexpr size_t OFF_QKVF  = 65929216;                   // fp32 2048*5120 = 41,943,040
constexpr size_t OFF_QB    = 107872256;                  // 16,777,216
constexpr size_t OFF_KB    = 124649472;                  // 2,097,152
constexpr size_t OFF_VTB   = 126746624;                  // 2,097,152

extern "C" void kernel_launch(void* const* d_in, const int* in_sizes, int n_in,
                              void* d_out, int out_size, void* d_ws, size_t ws_size,
                              hipStream_t stream) {
  const float* x  = (const float*)d_in[0];
  const float* wq = (const float*)d_in[1];
  const float* wk = (const float*)d_in[2];
  const float* wv = (const float*)d_in[3];
  const float* wo = (const float*)d_in[4];
  const int* pos  = (const int*)d_in[5];
  float* out = (float*)d_out;
  char* ws = (char*)d_ws;

  unsigned short* xb    = (unsigned short*)(ws + OFF_XB);
  unsigned short* wqkvt = (unsigned short*)(ws + OFF_WQKVT);
  unsigned short* wot   = (unsigned short*)(ws + OFF_WOT);
  float* ct             = (float*)(ws + OFF_COS);
  float* st             = (float*)(ws + OFF_SIN);
  float* qkvf           = (float*)(ws + OFF_QKVF);
  unsigned short* qbuf  = (unsigned short*)(ws + OFF_QB);
  unsigned short* kbuf  = (unsigned short*)(ws + OFF_KB);
  unsigned short* vtb   = (unsigned short*)(ws + OFF_VTB);
  unsigned short* attnb = (unsigned short*)(ws + OFF_QKVF);  // qkvf dead after packers

  cast_x_kernel<<<(M_TOK * HIDDEN / 4 + 255) / 256, 256, 0, stream>>>(x, xb, M_TOK * HIDDEN / 4);
  rope_table<<<(M_TOK * 32) / 256, 256, 0, stream>>>(pos, ct, st);
  transpose_cast<<<dim3(NQ / 32, HIDDEN / 32), dim3(32, 8), 0, stream>>>(
      wq, NQ, wqkvt, HIDDEN, NQ);
  transpose_cast<<<dim3(NKVD / 32, HIDDEN / 32), dim3(32, 8), 0, stream>>>(
      wk, NKVD, wqkvt + (size_t)NQ * HIDDEN, HIDDEN, NKVD);
  transpose_cast<<<dim3(NKVD / 32, HIDDEN / 32), dim3(32, 8), 0, stream>>>(
      wv, NKVD, wqkvt + (size_t)(NQ + NKVD) * HIDDEN, HIDDEN, NKVD);
  transpose_cast<<<dim3(NOUT_PAD / 32, NQ / 32), dim3(32, 8), 0, stream>>>(
      wo, NOUT, wot, NQ, NOUT);
  // QKV projection: 128^2 tile, grid 40x16 = 640 blocks, K=2880, fp32 out
  gemm128<<<dim3(NQKV / 128, M_TOK / 128), 256, 0, stream>>>(
      xb, wqkvt, qkvf, HIDDEN, NQKV, NQKV);
  // RoPE + pack
  rope_q_pack<<<(M_TOK * NH * 32) / 256, 256, 0, stream>>>(qkvf, ct, st, qbuf);
  rope_k_pack<<<(M_TOK * NKV * 32) / 256, 256, 0, stream>>>(qkvf, ct, st, kbuf);
  for (int b = 0; b < BB; ++b)
    transpose_cast<<<dim3(NKVD / 32, SS / 32), dim3(32, 8), 0, stream>>>(
        qkvf + (size_t)b * SS * NQKV + (NQ + NKVD), NQKV,
        vtb + (size_t)b * NKVD * SS, SS, NKVD);
  // attention (qkvf dead; attnb overlays it)
  attn_fwd<<<dim3(4, BB * NH), 512, 0, stream>>>(qbuf, kbuf, vtb, attnb);
  // output projection: grid 23x16 = 368 blocks, K=4096, fp32 direct to d_out
  gemm128<<<dim3(NOUT_PAD / 128, M_TOK / 128), 256, 0, stream>>>(
      attnb, wot, out, NQ, NOUT, NOUT);
}

// Round 11
// 256.713 us; speedup vs baseline: 1.1725x; 1.0567x over previous
//
#include <hip/hip_runtime.h>

// ---- problem constants ----
#define BB 2
#define SS 1024
#define HIDDEN 2880
#define NH 64
#define NKV 8
#define HD 64
#define M_TOK 2048          // B*S
#define NQ 4096             // NH*HD
#define NKVD 512            // NKV*HD
#define NQKV 5120           // NQ + 2*NKVD
#define NOUT 2880
#define NOUT_PAD 2944       // 23*128

typedef __attribute__((ext_vector_type(8))) short short8;
typedef __attribute__((ext_vector_type(4))) float f32x4;

__device__ __forceinline__ unsigned short f2b(float x) {
  union { float f; unsigned u; } v; v.f = x;
  unsigned r = (v.u + 0x7FFFu + ((v.u >> 16) & 1u)) >> 16;
  return (unsigned short)r;
}

__device__ __forceinline__ void gload16(const void* g, void* l) {
  __builtin_amdgcn_global_load_lds(
      (const __attribute__((address_space(1))) void*)g,
      (__attribute__((address_space(3))) void*)l, 16, 0, 0);
}

// ---- cast x (fp32 -> bf16), vectorized ----
__global__ __launch_bounds__(256) void cast_x_kernel(const float* __restrict__ in,
                                                     unsigned short* __restrict__ out,
                                                     int n4) {
  int idx = blockIdx.x * 256 + threadIdx.x;
  if (idx >= n4) return;
  float4 v = ((const float4*)in)[idx];
  ushort4 o;
  o.x = f2b(v.x); o.y = f2b(v.y); o.z = f2b(v.z); o.w = f2b(v.w);
  ((ushort4*)out)[idx] = o;
}

// ---- transpose + cast (fp32 in): out[n*K + k] = (bf16) in[k*ldin + n] ----
__global__ __launch_bounds__(256) void transpose_cast(const float* __restrict__ in,
                                                      long ldin,
                                                      unsigned short* __restrict__ out,
                                                      int K, int N) {
  __shared__ float t[32][33];
  const int n0 = blockIdx.x * 32, k0 = blockIdx.y * 32;
  const int tx = threadIdx.x, ty = threadIdx.y;
#pragma unroll
  for (int i = 0; i < 4; ++i) {
    int k = k0 + ty + i * 8;
    int n = n0 + tx;
    t[ty + i * 8][tx] = (n < N) ? in[(long)k * ldin + n] : 0.f;
  }
  __syncthreads();
#pragma unroll
  for (int i = 0; i < 4; ++i) {
    int n = n0 + ty + i * 8;
    int k = k0 + tx;
    out[(long)n * K + k] = f2b(t[tx][ty + i * 8]);
  }
}

// ---- RoPE cos/sin table: [2048][32] each ----
__global__ __launch_bounds__(256) void rope_table(const int* __restrict__ pos,
                                                  float* __restrict__ ct,
                                                  float* __restrict__ st) {
  int tid = blockIdx.x * 256 + threadIdx.x;   // < 2048*32
  int t = tid >> 5, i = tid & 31;
  float p = (float)pos[t];
  float f = p * expf(-(float)i * (11.918390573078392f / 32.f));
  ct[tid] = cosf(f);
  st[tid] = sinf(f);
}

// ==== shared GEMM body macro: 128x128 tile, BK=64, 4 waves (2x2), m97 structure ====
// Declares/computes: acc[4][4], tid/lane/w/m16/g4/wr/wc, bm/bn. K-loop complete.
#define GEMM128_BODY(Aptr, Bptr, lda)                                                     \
  __shared__ char lA[128 * 128];                                                          \
  __shared__ char lB[128 * 128];                                                          \
  const int tid = threadIdx.x;                                                            \
  const int lane = tid & 63;                                                              \
  const int w = tid >> 6;                                                                 \
  const int m16 = lane & 15, g4 = lane >> 4;                                              \
  const int wr = w >> 1, wc = w & 1;                                                      \
  const int bm = blockIdx.y * 128, bn = blockIdx.x * 128;                                 \
  const size_t strb = (size_t)(lda) * 2;                                                  \
  const int srow = tid >> 3;                                                              \
  const int scolb = ((tid & 7) * 16) ^ ((srow & 7) << 4);                                 \
  const int sdst = w * 1024;                                                              \
  const char* ga0 = (const char*)(Aptr) + (size_t)(bm + srow) * strb + scolb;             \
  const char* gb0 = (const char*)(Bptr) + (size_t)(bn + srow) * strb + scolb;             \
  const int swz = (m16 & 7) << 4;                                                         \
  const int kc0 = (g4 * 16) ^ swz;                                                        \
  const int kc1 = (64 + g4 * 16) ^ swz;                                                   \
  f32x4 acc[4][4];                                                                        \
  _Pragma("unroll") for (int i = 0; i < 4; ++i)                                           \
  _Pragma("unroll") for (int j = 0; j < 4; ++j) acc[i][j] = (f32x4){0.f, 0.f, 0.f, 0.f};  \
  const int NT = (lda) >> 6;                                                              \
  for (int t = 0; t < NT; ++t) {                                                          \
    const size_t ko = (size_t)t * 128;                                                    \
    __syncthreads();                                                                      \
    _Pragma("unroll") for (int i = 0; i < 4; ++i) {                                       \
      gload16(ga0 + (size_t)(i * 32) * strb + ko, lA + i * 4096 + sdst);                  \
      gload16(gb0 + (size_t)(i * 32) * strb + ko, lB + i * 4096 + sdst);                  \
    }                                                                                     \
    __syncthreads();                                                                      \
    short8 af[4][2], bf[4][2];                                                            \
    _Pragma("unroll") for (int mq = 0; mq < 4; ++mq) {                                    \
      const int row = wr * 64 + mq * 16 + m16;                                            \
      af[mq][0] = *(const short8*)(lA + row * 128 + kc0);                                 \
      af[mq][1] = *(const short8*)(lA + row * 128 + kc1);                                 \
    }                                                                                     \
    _Pragma("unroll") for (int nf = 0; nf < 4; ++nf) {                                    \
      const int row = wc * 64 + nf * 16 + m16;                                            \
      bf[nf][0] = *(const short8*)(lB + row * 128 + kc0);                                 \
      bf[nf][1] = *(const short8*)(lB + row * 128 + kc1);                                 \
    }                                                                                     \
    __builtin_amdgcn_s_setprio(1);                                                        \
    _Pragma("unroll") for (int mq = 0; mq < 4; ++mq)                                      \
    _Pragma("unroll") for (int nf = 0; nf < 4; ++nf) {                                    \
      acc[mq][nf] = __builtin_amdgcn_mfma_f32_16x16x32_bf16(af[mq][0], bf[nf][0], acc[mq][nf], 0, 0, 0); \
      acc[mq][nf] = __builtin_amdgcn_mfma_f32_16x16x32_bf16(af[mq][1], bf[nf][1], acc[mq][nf], 0, 0, 0); \
    }                                                                                     \
    __builtin_amdgcn_s_setprio(0);                                                        \
  }

// ---- plain GEMM (fp32 C out) -- used for wo projection ----
__global__ __launch_bounds__(256, 3) void gemm128(const unsigned short* __restrict__ A,
                                                  const unsigned short* __restrict__ Bt,
                                                  float* __restrict__ C,
                                                  int lda, int ldc, int Nvalid) {
  GEMM128_BODY(A, Bt, lda)
#pragma unroll
  for (int mq = 0; mq < 4; ++mq) {
    const size_t row = bm + wr * 64 + mq * 16 + g4 * 4;
#pragma unroll
    for (int nf = 0; nf < 4; ++nf) {
      const int col = bn + wc * 64 + nf * 16 + m16;
      if (col < Nvalid) {
#pragma unroll
        for (int r = 0; r < 4; ++r)
          C[(row + r) * (size_t)ldc + col] = acc[mq][nf][r];
      }
    }
  }
}

// ---- QKV GEMM with fused RoPE + pack epilogue ----
// Output col regions are block-uniform (bn multiple of 128):
//   bn < 4096 : Q heads -> RoPE (scaled 1/8) -> qb[b][h][s][d]
//   bn < 4608 : K heads -> RoPE -> kb[b][hk][s][d]
//   else      : V       -> transposed -> vtb[b][d][s]
// RoPE pair (i, i+32) of one head lives in acc[mq][nf] / acc[mq][nf+2] of the
// SAME thread (col = nf*16+m16; wave spans exactly one 64-col head).
__global__ __launch_bounds__(256, 3) void gemm128_qkv(const unsigned short* __restrict__ A,
                                                      const unsigned short* __restrict__ Bt,
                                                      const float* __restrict__ ct,
                                                      const float* __restrict__ st,
                                                      unsigned short* __restrict__ qb,
                                                      unsigned short* __restrict__ kb,
                                                      unsigned short* __restrict__ vtb,
                                                      int lda) {
  GEMM128_BODY(A, Bt, lda)
  const int region = (bn < 4096) ? 0 : ((bn < 4608) ? 1 : 2);
#pragma unroll
  for (int mq = 0; mq < 4; ++mq) {
    const int row = bm + wr * 64 + mq * 16 + g4 * 4;   // token index base (+r)
    if (region == 2) {
#pragma unroll
      for (int nf = 0; nf < 4; ++nf) {
        const int d = (bn - 4608) + wc * 64 + nf * 16 + m16;
#pragma unroll
        for (int r = 0; r < 4; ++r) {
          const int t = row + r;
          const int b = t >> 10, sidx = t & 1023;
          vtb[((size_t)(b * NKVD + d)) * SS + sidx] = f2b(acc[mq][nf][r]);
        }
      }
    } else {
#pragma unroll
      for (int nf = 0; nf < 2; ++nf) {
        const int i = nf * 16 + m16;
#pragma unroll
        for (int r = 0; r < 4; ++r) {
          const int t = row + r;
          const int b = t >> 10, sidx = t & 1023;
          const float x1 = acc[mq][nf][r], x2 = acc[mq][nf + 2][r];
          const float c = ct[t * 32 + i], s = st[t * 32 + i];
          if (region == 0) {
            const int h = (bn >> 6) + wc;
            unsigned short* dst = qb + (((size_t)(b * NH + h)) * SS + sidx) * HD;
            dst[i]      = f2b((x1 * c - x2 * s) * 0.125f);
            dst[i + 32] = f2b((x1 * s + x2 * c) * 0.125f);
          } else {
            const int hk = ((bn - 4096) >> 6) + wc;
            unsigned short* dst = kb + (((size_t)(b * NKV + hk)) * SS + sidx) * HD;
            dst[i]      = f2b(x1 * c - x2 * s);
            dst[i + 32] = f2b(x1 * s + x2 * c);
          }
        }
      }
    }
  }
}

// ---- flash attention (unchanged, validated R2-R10) ----
__global__ __launch_bounds__(512) void attn_fwd(const unsigned short* __restrict__ qb,
                                                const unsigned short* __restrict__ kb,
                                                const unsigned short* __restrict__ vtb,
                                                unsigned short* __restrict__ ao) {
  __shared__ unsigned short kB[2][64 * 64];
  __shared__ unsigned short vB[2][64 * 64];
  __shared__ unsigned short pB[8][32 * 64];
  const int tid = threadIdx.x, lane = tid & 63, w = tid >> 6;
  const int qblk = blockIdx.x;
  const int bh = blockIdx.y;
  const int b = bh >> 6, h = bh & 63, hkv = h >> 3;
  const int m16 = lane & 15, g4 = lane >> 4;
  const int rbase = qblk * 256 + w * 32;

  const unsigned short* qp =
      qb + (((size_t)(b * NH + h)) * SS + rbase + m16) * HD + g4 * 8;
  const short8 q00 = *(const short8*)(qp);
  const short8 q01 = *(const short8*)(qp + 32);
  const short8 q10 = *(const short8*)(qp + 16 * HD);
  const short8 q11 = *(const short8*)(qp + 16 * HD + 32);

  const char* kbp = (const char*)(kb + ((size_t)(b * NKV + hkv)) * SS * HD);
  const char* vbp = (const char*)(vtb + ((size_t)(b * NKV + hkv)) * HD * SS);

  const int lrow = lane >> 3;
  const int lcolb = ((lane & 7) * 16) ^ ((lrow & 7) << 4);
  unsigned short* kDst0 = &kB[0][w * 512];
  unsigned short* kDst1 = &kB[1][w * 512];
  unsigned short* vDst0 = &vB[0][w * 512];
  unsigned short* vDst1 = &vB[1][w * 512];
  const size_t kRowOff = (size_t)(w * 8 + lrow) * 128 + lcolb;
  const size_t vRowOff = (size_t)(w * 8 + lrow) * 2048 + lcolb;

  const short8 ones = {(short)0x3F80, (short)0x3F80, (short)0x3F80, (short)0x3F80,
                       (short)0x3F80, (short)0x3F80, (short)0x3F80, (short)0x3F80};

  f32x4 o0[4], o1[4];
#pragma unroll
  for (int n = 0; n < 4; ++n) { o0[n] = (f32x4){0,0,0,0}; o1[n] = (f32x4){0,0,0,0}; }
  f32x4 lacc0 = (f32x4){0,0,0,0}, lacc1 = (f32x4){0,0,0,0};
  float mrow0[4] = {-1e30f,-1e30f,-1e30f,-1e30f};
  float mrow1[4] = {-1e30f,-1e30f,-1e30f,-1e30f};

  char* pw = (char*)pB[w];
  const int swz_m = (m16 & 7) << 4;
  const int nt = (qblk + 1) * 4;

  gload16(kbp + kRowOff, kDst0);
  gload16(vbp + vRowOff, vDst0);
  __syncthreads();

  for (int t = 0; t < nt; ++t) {
    const int k0 = t * 64;
    const char* kLds = (const char*)kB[t & 1];
    const char* vLds = (const char*)vB[t & 1];
    if (t + 1 < nt) {
      if (t & 1) { gload16(kbp + (size_t)(t + 1) * 8192 + kRowOff, kDst0);
                   gload16(vbp + (size_t)(t + 1) * 128  + vRowOff, vDst0); }
      else       { gload16(kbp + (size_t)(t + 1) * 8192 + kRowOff, kDst1);
                   gload16(vbp + (size_t)(t + 1) * 128  + vRowOff, vDst1); }
    }
    if (k0 < rbase + 32) {
      short8 kf0[4], kf1[4];
#pragma unroll
      for (int kf = 0; kf < 4; ++kf) {
        const int rb = (kf * 16 + m16) * 128;
        kf0[kf] = *(const short8*)(kLds + ((rb + g4 * 16) ^ swz_m));
        kf1[kf] = *(const short8*)(kLds + ((rb + 64 + g4 * 16) ^ swz_m));
      }
      f32x4 s0[4], s1[4];
      __builtin_amdgcn_s_setprio(1);
#pragma unroll
      for (int kf = 0; kf < 4; ++kf) {
        f32x4 z = (f32x4){0,0,0,0};
        z = __builtin_amdgcn_mfma_f32_16x16x32_bf16(q00, kf0[kf], z, 0, 0, 0);
        z = __builtin_amdgcn_mfma_f32_16x16x32_bf16(q01, kf1[kf], z, 0, 0, 0);
        s0[kf] = z;
        f32x4 z2 = (f32x4){0,0,0,0};
        z2 = __builtin_amdgcn_mfma_f32_16x16x32_bf16(q10, kf0[kf], z2, 0, 0, 0);
        z2 = __builtin_amdgcn_mfma_f32_16x16x32_bf16(q11, kf1[kf], z2, 0, 0, 0);
        s1[kf] = z2;
      }
      __builtin_amdgcn_s_setprio(0);
      if (k0 + 63 >= rbase) {
#pragma unroll
        for (int kf = 0; kf < 4; ++kf)
#pragma unroll
          for (int r = 0; r < 4; ++r) {
            const int col = k0 + kf * 16 + m16;
            if (col > rbase + g4 * 4 + r)      s0[kf][r] = -1e30f;
            if (col > rbase + 16 + g4 * 4 + r) s1[kf][r] = -1e30f;
          }
      }
      int grow = 0;
#pragma unroll
      for (int kf = 0; kf < 4; ++kf)
#pragma unroll
        for (int r = 0; r < 4; ++r) {
          grow |= (s0[kf][r] > mrow0[r] + 8.f);
          grow |= (s1[kf][r] > mrow1[r] + 8.f);
        }
      if (__any(grow)) {
        float mx0[4], mx1[4];
#pragma unroll
        for (int r = 0; r < 4; ++r) {
          mx0[r] = fmaxf(fmaxf(s0[0][r], s0[1][r]), fmaxf(s0[2][r], s0[3][r]));
          mx1[r] = fmaxf(fmaxf(s1[0][r], s1[1][r]), fmaxf(s1[2][r], s1[3][r]));
        }
#pragma unroll
        for (int off = 1; off <= 8; off <<= 1)
#pragma unroll
          for (int r = 0; r < 4; ++r) {
            mx0[r] = fmaxf(mx0[r], __shfl_xor(mx0[r], off));
            mx1[r] = fmaxf(mx1[r], __shfl_xor(mx1[r], off));
          }
#pragma unroll
        for (int r = 0; r < 4; ++r) {
          float mn0 = fmaxf(mrow0[r], mx0[r]);
          float sc0 = __expf(mrow0[r] - mn0);
          mrow0[r] = mn0; lacc0[r] *= sc0;
          float mn1 = fmaxf(mrow1[r], mx1[r]);
          float sc1 = __expf(mrow1[r] - mn1);
          mrow1[r] = mn1; lacc1[r] *= sc1;
#pragma unroll
          for (int n = 0; n < 4; ++n) { o0[n][r] *= sc0; o1[n][r] *= sc1; }
        }
      }
#pragma unroll
      for (int kf = 0; kf < 4; ++kf)
#pragma unroll
        for (int r = 0; r < 4; ++r) {
          const int colb = (kf * 16 + m16) * 2;
          int row = g4 * 4 + r;
          *(unsigned short*)(pw + ((row * 128 + colb) ^ ((row & 7) << 4))) =
              f2b(__expf(s0[kf][r] - mrow0[r]));
          row += 16;
          *(unsigned short*)(pw + ((row * 128 + colb) ^ ((row & 7) << 4))) =
              f2b(__expf(s1[kf][r] - mrow1[r]));
        }
      const int prb0 = m16 * 128, prb1 = (16 + m16) * 128;
      short8 pf00 = *(const short8*)(pw + ((prb0 + g4 * 16) ^ swz_m));
      short8 pf01 = *(const short8*)(pw + ((prb0 + 64 + g4 * 16) ^ swz_m));
      short8 pf10 = *(const short8*)(pw + ((prb1 + g4 * 16) ^ swz_m));
      short8 pf11 = *(const short8*)(pw + ((prb1 + 64 + g4 * 16) ^ swz_m));
      __builtin_amdgcn_s_setprio(1);
      lacc0 = __builtin_amdgcn_mfma_f32_16x16x32_bf16(pf00, ones, lacc0, 0, 0, 0);
      lacc0 = __builtin_amdgcn_mfma_f32_16x16x32_bf16(pf01, ones, lacc0, 0, 0, 0);
      lacc1 = __builtin_amdgcn_mfma_f32_16x16x32_bf16(pf10, ones, lacc1, 0, 0, 0);
      lacc1 = __builtin_amdgcn_mfma_f32_16x16x32_bf16(pf11, ones, lacc1, 0, 0, 0);
#pragma unroll
      for (int n = 0; n < 4; ++n) {
        const int rb = (n * 16 + m16) * 128;
        short8 vf0 = *(const short8*)(vLds + ((rb + g4 * 16) ^ swz_m));
        short8 vf1 = *(const short8*)(vLds + ((rb + 64 + g4 * 16) ^ swz_m));
        o0[n] = __builtin_amdgcn_mfma_f32_16x16x32_bf16(pf00, vf0, o0[n], 0, 0, 0);
        o0[n] = __builtin_amdgcn_mfma_f32_16x16x32_bf16(pf01, vf1, o0[n], 0, 0, 0);
        o1[n] = __builtin_amdgcn_mfma_f32_16x16x32_bf16(pf10, vf0, o1[n], 0, 0, 0);
        o1[n] = __builtin_amdgcn_mfma_f32_16x16x32_bf16(pf11, vf1, o1[n], 0, 0, 0);
      }
      __builtin_amdgcn_s_setprio(0);
    }
    __syncthreads();
  }

  float inv0[4], inv1[4];
#pragma unroll
  for (int r = 0; r < 4; ++r) { inv0[r] = 1.f / lacc0[r]; inv1[r] = 1.f / lacc1[r]; }
  const size_t row0 = (size_t)b * SS + rbase + g4 * 4;
#pragma unroll
  for (int n = 0; n < 4; ++n)
#pragma unroll
    for (int r = 0; r < 4; ++r) {
      ao[(row0 + r) * (size_t)NQ + h * 64 + n * 16 + m16] = f2b(o0[n][r] * inv0[r]);
      ao[(row0 + 16 + r) * (size_t)NQ + h * 64 + n * 16 + m16] = f2b(o1[n][r] * inv1[r]);
    }
}

// ---- workspace layout (bytes), total 103,677,952 ----
constexpr size_t OFF_XB    = 0;                          // 11,796,480
constexpr size_t OFF_WQKVT = 11796480;                   // 29,491,200
constexpr size_t OFF_WOT   = 41287680;                   // 24,117,248
constexpr size_t OFF_COS   = 65404928;                   // 262,144
constexpr size_t OFF_SIN   = 65667072;                   // 262,144
constexpr size_t OFF_QB    = 65929216;                   // 16,777,216
constexpr size_t OFF_KB    = 82706432;                   // 2,097,152
constexpr size_t OFF_VTB   = 84803584;                   // 2,097,152
constexpr size_t OFF_ATTNB = 86900736;                   // 16,777,216

extern "C" void kernel_launch(void* const* d_in, const int* in_sizes, int n_in,
                              void* d_out, int out_size, void* d_ws, size_t ws_size,
                              hipStream_t stream) {
  const float* x  = (const float*)d_in[0];
  const float* wq = (const float*)d_in[1];
  const float* wk = (const float*)d_in[2];
  const float* wv = (const float*)d_in[3];
  const float* wo = (const float*)d_in[4];
  const int* pos  = (const int*)d_in[5];
  float* out = (float*)d_out;
  char* ws = (char*)d_ws;

  unsigned short* xb    = (unsigned short*)(ws + OFF_XB);
  unsigned short* wqkvt = (unsigned short*)(ws + OFF_WQKVT);
  unsigned short* wot   = (unsigned short*)(ws + OFF_WOT);
  float* ct             = (float*)(ws + OFF_COS);
  float* st             = (float*)(ws + OFF_SIN);
  unsigned short* qbuf  = (unsigned short*)(ws + OFF_QB);
  unsigned short* kbuf  = (unsigned short*)(ws + OFF_KB);
  unsigned short* vtb   = (unsigned short*)(ws + OFF_VTB);
  unsigned short* attnb = (unsigned short*)(ws + OFF_ATTNB);

  cast_x_kernel<<<(M_TOK * HIDDEN / 4 + 255) / 256, 256, 0, stream>>>(x, xb, M_TOK * HIDDEN / 4);
  rope_table<<<(M_TOK * 32) / 256, 256, 0, stream>>>(pos, ct, st);
  transpose_cast<<<dim3(NQ / 32, HIDDEN / 32), dim3(32, 8), 0, stream>>>(
      wq, NQ, wqkvt, HIDDEN, NQ);
  transpose_cast<<<dim3(NKVD / 32, HIDDEN / 32), dim3(32, 8), 0, stream>>>(
      wk, NKVD, wqkvt + (size_t)NQ * HIDDEN, HIDDEN, NKVD);
  transpose_cast<<<dim3(NKVD / 32, HIDDEN / 32), dim3(32, 8), 0, stream>>>(
      wv, NKVD, wqkvt + (size_t)(NQ + NKVD) * HIDDEN, HIDDEN, NKVD);
  transpose_cast<<<dim3(NOUT_PAD / 32, NQ / 32), dim3(32, 8), 0, stream>>>(
      wo, NOUT, wot, NQ, NOUT);
  // QKV projection with fused RoPE+pack epilogue: grid 40x16 = 640 blocks
  gemm128_qkv<<<dim3(NQKV / 128, M_TOK / 128), 256, 0, stream>>>(
      xb, wqkvt, ct, st, qbuf, kbuf, vtb, HIDDEN);
  // attention
  attn_fwd<<<dim3(4, BB * NH), 512, 0, stream>>>(qbuf, kbuf, vtb, attnb);
  // output projection: grid 23x16 = 368 blocks, fp32 direct to d_out
  gemm128<<<dim3(NOUT_PAD / 128, M_TOK / 128), 256, 0, stream>>>(
      attnb, wot, out, NQ, NOUT, NOUT);
}